// Round 1
// baseline (1639.368 us; speedup 1.0000x reference)
//
#include <hip/hip_runtime.h>
#include <math.h>

#define NB 32
#define NN 64
#define NS 9
#define NCS 32
#define NC 128
#define AVGF 49.0f

__device__ __forceinline__ float lrelu(float x) { return x > 0.0f ? x : 0.01f * x; }

// ---------------- prep: mask1, eq1to2 projections ----------------
__global__ __launch_bounds__(256) void k_prep(
    const float* __restrict__ scalars, const int* __restrict__ nobj,
    const float* __restrict__ w_in,
    float* __restrict__ mask1, float* __restrict__ P0,
    float* __restrict__ P1, float* __restrict__ P2,
    float* __restrict__ Ps3, float* __restrict__ Ps4)
{
    int b = blockIdx.x, tid = threadIdx.x;
    __shared__ float xs[NN][NS];
    __shared__ float ss[NS];
    int cnt = nobj[b];
    for (int idx = tid; idx < NN * NS; idx += 256) {
        int i = idx / NS, s = idx - i * NS;
        xs[i][s] = (i < cnt) ? scalars[(b * NN + i) * NS + s] : 0.0f;
    }
    if (tid < NN) mask1[b * NN + tid] = (tid < cnt) ? 1.0f : 0.0f;
    __syncthreads();
    if (tid < NS) {
        float a = 0.f;
        for (int i = 0; i < NN; ++i) a += xs[i][tid];
        ss[tid] = a / AVGF;
    }
    __syncthreads();
    for (int idx = tid; idx < NN * NCS; idx += 256) {
        int i = idx >> 5, d = idx & 31;
        float a0 = 0.f, a1 = 0.f, a2 = 0.f;
        #pragma unroll
        for (int s = 0; s < NS; ++s) {
            float x = xs[i][s];
            a0 += x * w_in[(0 * NS + s) * NCS + d];
            a1 += x * w_in[(1 * NS + s) * NCS + d];
            a2 += x * w_in[(2 * NS + s) * NCS + d];
        }
        P0[(b * NN + i) * NCS + d] = a0;
        P1[(b * NN + i) * NCS + d] = a1;
        P2[(b * NN + i) * NCS + d] = a2;
    }
    if (tid < NCS) {
        float a3 = 0.f, a4 = 0.f;
        #pragma unroll
        for (int s = 0; s < NS; ++s) {
            a3 += ss[s] * w_in[(3 * NS + s) * NCS + tid];
            a4 += ss[s] * w_in[(4 * NS + s) * NCS + tid];
        }
        Ps3[b * NCS + tid] = a3;
        Ps4[b * NCS + tid] = a4;
    }
}

// ---------------- build T0: eq1to2 (ch 0..31) + slog invariants (ch 32..127) ----------------
__global__ __launch_bounds__(256) void k_build(
    const float* __restrict__ momenta, const float* __restrict__ mask1,
    const float* __restrict__ P0, const float* __restrict__ P1,
    const float* __restrict__ P2, const float* __restrict__ Ps3,
    const float* __restrict__ Ps4, const float* __restrict__ b_in,
    const float* __restrict__ w_lin, const float* __restrict__ alpha,
    float* __restrict__ T)
{
    int blk = blockIdx.x;
    int b = blk >> 6, i = blk & 63;
    int tid = threadIdx.x;
    __shared__ float dots[NN];
    __shared__ float mj[NN];
    if (tid < NN) {
        int j = tid;
        const float* pi = momenta + (size_t)(b * NN + i) * 4;
        const float* pj = momenta + (size_t)(b * NN + j) * 4;
        dots[j] = pi[0] * pj[0] - pi[1] * pj[1] - pi[2] * pj[2] - pi[3] * pj[3];
        mj[j] = mask1[b * NN + j];
    }
    __syncthreads();
    float mi = mask1[b * NN + i];
    for (int idx = tid; idx < NN * NC; idx += 256) {
        int j = idx >> 7, c = idx & 127;
        float m2 = mi * mj[j];
        float v;
        if (c < NCS) {
            v = P0[(b * NN + i) * NCS + c] + P1[(b * NN + j) * NCS + c]
              + Ps3[b * NCS + c] + b_in[c];
            if (i == j) v += P2[(b * NN + i) * NCS + c] + Ps4[b * NCS + c];
            v = lrelu(v) * m2;
        } else {
            int c2 = c - NCS;
            float r = dots[j] * w_lin[c2];
            v = alpha[c2] * copysignf(log1pf(fabsf(r)), r) * m2;
        }
        T[(size_t)blk * NN * NC + idx] = v;
    }
}

// ---------------- MessageNet: out = lrelu(in @ W + bias) * mask2 ----------------
// block per (b,i): 64 rows x 128 cols; thread tile 4j x 8c
__global__ __launch_bounds__(256) void k_msg(
    const float* __restrict__ in, const float* __restrict__ W,
    const float* __restrict__ bias, const float* __restrict__ mask1,
    float* __restrict__ out)
{
    int blk = blockIdx.x;
    int b = blk >> 6, i = blk & 63;
    int tid = threadIdx.x;
    __shared__ float In_t[NC][NN];  // [k][j], j-index XOR-swizzled by (k&7)<<2
    const size_t base = (size_t)blk * NN * NC;
    for (int idx = tid; idx < NN * NC; idx += 256) {
        int j = idx >> 7, c = idx & 127;
        In_t[c][j ^ ((c & 7) << 2)] = in[base + idx];
    }
    __syncthreads();
    int jg = tid >> 4, cg = tid & 15;
    float acc[4][8];
    #pragma unroll
    for (int a = 0; a < 4; ++a)
        #pragma unroll
        for (int q = 0; q < 8; ++q) acc[a][q] = 0.f;
    const float* Wp = W + cg * 8;
    #pragma unroll 4
    for (int k = 0; k < NC; ++k) {
        float4 a4 = *(const float4*)&In_t[k][(jg << 2) ^ ((k & 7) << 2)];
        float4 w0 = *(const float4*)&Wp[k * NC];
        float4 w1 = *(const float4*)&Wp[k * NC + 4];
        float av[4] = {a4.x, a4.y, a4.z, a4.w};
        #pragma unroll
        for (int a = 0; a < 4; ++a) {
            acc[a][0] += av[a] * w0.x; acc[a][1] += av[a] * w0.y;
            acc[a][2] += av[a] * w0.z; acc[a][3] += av[a] * w0.w;
            acc[a][4] += av[a] * w1.x; acc[a][5] += av[a] * w1.y;
            acc[a][6] += av[a] * w1.z; acc[a][7] += av[a] * w1.w;
        }
    }
    float mi = mask1[b * NN + i];
    float bs[8];
    #pragma unroll
    for (int q = 0; q < 8; ++q) bs[q] = bias[cg * 8 + q];
    #pragma unroll
    for (int a = 0; a < 4; ++a) {
        int j = (jg << 2) + a;
        float m2 = mi * mask1[b * NN + j];
        float4 o0, o1;
        o0.x = lrelu(acc[a][0] + bs[0]) * m2;
        o0.y = lrelu(acc[a][1] + bs[1]) * m2;
        o0.z = lrelu(acc[a][2] + bs[2]) * m2;
        o0.w = lrelu(acc[a][3] + bs[3]) * m2;
        o1.x = lrelu(acc[a][4] + bs[4]) * m2;
        o1.y = lrelu(acc[a][5] + bs[5]) * m2;
        o1.z = lrelu(acc[a][6] + bs[6]) * m2;
        o1.w = lrelu(acc[a][7] + bs[7]) * m2;
        *(float4*)&out[base + (size_t)j * NC + cg * 8] = o0;
        *(float4*)&out[base + (size_t)j * NC + cg * 8 + 4] = o1;
    }
}

// ---------------- reductions: row sums, col sums, diag ----------------
__global__ __launch_bounds__(128) void k_red1(
    const float* __restrict__ U, float* __restrict__ rsum,
    float* __restrict__ csum, float* __restrict__ diag)
{
    int blk = blockIdx.x;
    int b = blk >> 6, i = blk & 63;
    int c = threadIdx.x;
    const float* Ub = U + (size_t)b * NN * NN * NC;
    float rs = 0.f, cs = 0.f;
    for (int j = 0; j < NN; ++j) {
        rs += Ub[((size_t)i * NN + j) * NC + c];
        cs += Ub[((size_t)j * NN + i) * NC + c];
    }
    rsum[(size_t)blk * NC + c] = rs / AVGF;
    csum[(size_t)blk * NC + c] = cs / AVGF;
    diag[(size_t)blk * NC + c] = Ub[((size_t)i * NN + i) * NC + c];
}

// ---------------- t, tr and global broadcast vectors G, Gd ----------------
__global__ __launch_bounds__(128) void k_red2(
    const float* __restrict__ rsum, const float* __restrict__ diag,
    const float* __restrict__ Weq, const float* __restrict__ eqb,
    const float* __restrict__ eqbd, float* __restrict__ G, float* __restrict__ Gd)
{
    int b = blockIdx.x;
    int c = threadIdx.x;
    __shared__ float ts[NC], trs[NC];
    float tt = 0.f, rr = 0.f;
    for (int i = 0; i < NN; ++i) {
        tt += rsum[(size_t)(b * NN + i) * NC + c];
        rr += diag[(size_t)(b * NN + i) * NC + c];
    }
    ts[c] = tt / AVGF;
    trs[c] = rr / AVGF;
    __syncthreads();
    float g = eqb[c], gd = eqbd[c];
    for (int k = 0; k < NC; ++k) {
        float tv = ts[k], rv = trs[k];
        g  += tv * Weq[(11 * NC + k) * NC + c] + rv * Weq[(13 * NC + k) * NC + c];
        gd += tv * Weq[(12 * NC + k) * NC + c] + rv * Weq[(14 * NC + k) * NC + c];
    }
    G[b * NC + c] = g;
    Gd[b * NC + c] = gd;
}

// ---------------- per-row broadcast vectors A (i), Bc (j), Dg (diag) ----------------
__global__ __launch_bounds__(256) void k_red3(
    const float* __restrict__ rsum, const float* __restrict__ csum,
    const float* __restrict__ diag, const float* __restrict__ Weq,
    float* __restrict__ A, float* __restrict__ Bc, float* __restrict__ Dg)
{
    int blk = blockIdx.x;          // 8 rows per block over [B*N]
    int row0 = blk * 8;
    int tid = threadIdx.x;
    int c = tid & 127, half = tid >> 7;
    __shared__ float ds[8][NC], rs[8][NC], cs[8][NC];
    for (int idx = tid; idx < 8 * NC; idx += 256) {
        int r = idx >> 7, cc = idx & 127;
        ds[r][cc] = diag[(size_t)(row0 + r) * NC + cc];
        rs[r][cc] = rsum[(size_t)(row0 + r) * NC + cc];
        cs[r][cc] = csum[(size_t)(row0 + r) * NC + cc];
    }
    __syncthreads();
    float aA[4] = {0, 0, 0, 0}, aB[4] = {0, 0, 0, 0}, aD[4] = {0, 0, 0, 0};
    for (int k = 0; k < NC; ++k) {
        float w2  = Weq[(2  * NC + k) * NC + c];
        float w3  = Weq[(3  * NC + k) * NC + c];
        float w4  = Weq[(4  * NC + k) * NC + c];
        float w5  = Weq[(5  * NC + k) * NC + c];
        float w6  = Weq[(6  * NC + k) * NC + c];
        float w7  = Weq[(7  * NC + k) * NC + c];
        float w8  = Weq[(8  * NC + k) * NC + c];
        float w9  = Weq[(9  * NC + k) * NC + c];
        float w10 = Weq[(10 * NC + k) * NC + c];
        #pragma unroll
        for (int r = 0; r < 4; ++r) {
            int rr = half * 4 + r;
            float dv = ds[rr][k], rv = rs[rr][k], cv = cs[rr][k];
            aA[r] += dv * w3 + rv * w5 + cv * w7;
            aB[r] += dv * w4 + rv * w6 + cv * w8;
            aD[r] += dv * w2 + rv * w9 + cv * w10;
        }
    }
    #pragma unroll
    for (int r = 0; r < 4; ++r) {
        size_t o = (size_t)(row0 + half * 4 + r) * NC + c;
        A[o] = aA[r];
        Bc[o] = aB[r];
        Dg[o] = aD[r];
    }
}

// ---------------- eq2to2 main: out = lrelu(U@W0 + U^T@W1 + A_i + Bc_j + G + diag terms) * mask2
__global__ __launch_bounds__(256) void k_eq_main(
    const float* __restrict__ U, const float* __restrict__ W0,
    const float* __restrict__ W1, const float* __restrict__ A,
    const float* __restrict__ Bc, const float* __restrict__ Dg,
    const float* __restrict__ G, const float* __restrict__ Gd,
    const float* __restrict__ mask1, float* __restrict__ out)
{
    int blk = blockIdx.x;
    int b = blk >> 6, i = blk & 63;
    int tid = threadIdx.x;
    __shared__ float Ur[NC][NN];  // Ur[k][j] = U[b,i,j,k] (swizzled)
    __shared__ float Uc[NC][NN];  // Uc[k][j] = U[b,j,i,k] (swizzled)
    const size_t base = (size_t)blk * NN * NC;
    for (int idx = tid; idx < NN * NC; idx += 256) {
        int j = idx >> 7, c = idx & 127;
        int sw = j ^ ((c & 7) << 2);
        Ur[c][sw] = U[base + idx];
        Uc[c][sw] = U[((size_t)(b * NN + j) * NN + i) * NC + c];
    }
    __syncthreads();
    int jg = tid >> 4, cg = tid & 15;
    float acc[4][8];
    #pragma unroll
    for (int a = 0; a < 4; ++a)
        #pragma unroll
        for (int q = 0; q < 8; ++q) acc[a][q] = 0.f;
    const float* W0p = W0 + cg * 8;
    const float* W1p = W1 + cg * 8;
    #pragma unroll 2
    for (int k = 0; k < NC; ++k) {
        int sw = (jg << 2) ^ ((k & 7) << 2);
        float4 a4 = *(const float4*)&Ur[k][sw];
        float4 c4 = *(const float4*)&Uc[k][sw];
        float4 w0a = *(const float4*)&W0p[k * NC];
        float4 w0b = *(const float4*)&W0p[k * NC + 4];
        float4 w1a = *(const float4*)&W1p[k * NC];
        float4 w1b = *(const float4*)&W1p[k * NC + 4];
        float av[4] = {a4.x, a4.y, a4.z, a4.w};
        float cv[4] = {c4.x, c4.y, c4.z, c4.w};
        #pragma unroll
        for (int a = 0; a < 4; ++a) {
            acc[a][0] += av[a] * w0a.x + cv[a] * w1a.x;
            acc[a][1] += av[a] * w0a.y + cv[a] * w1a.y;
            acc[a][2] += av[a] * w0a.z + cv[a] * w1a.z;
            acc[a][3] += av[a] * w0a.w + cv[a] * w1a.w;
            acc[a][4] += av[a] * w0b.x + cv[a] * w1b.x;
            acc[a][5] += av[a] * w0b.y + cv[a] * w1b.y;
            acc[a][6] += av[a] * w0b.z + cv[a] * w1b.z;
            acc[a][7] += av[a] * w0b.w + cv[a] * w1b.w;
        }
    }
    float mi = mask1[b * NN + i];
    const float* Ai = A + (size_t)(b * NN + i) * NC + cg * 8;
    const float* Gb = G + (size_t)b * NC + cg * 8;
    const float* Dgi = Dg + (size_t)(b * NN + i) * NC + cg * 8;
    const float* Gdb = Gd + (size_t)b * NC + cg * 8;
    #pragma unroll
    for (int a = 0; a < 4; ++a) {
        int j = (jg << 2) + a;
        float m2 = mi * mask1[b * NN + j];
        const float* Bj = Bc + (size_t)(b * NN + j) * NC + cg * 8;
        float4 o0, o1;
        float v[8];
        #pragma unroll
        for (int q = 0; q < 8; ++q) {
            v[q] = acc[a][q] + Ai[q] + Bj[q] + Gb[q];
            if (i == j) v[q] += Dgi[q] + Gdb[q];
            v[q] = lrelu(v[q]) * m2;
        }
        o0.x = v[0]; o0.y = v[1]; o0.z = v[2]; o0.w = v[3];
        o1.x = v[4]; o1.y = v[5]; o1.z = v[6]; o1.w = v[7];
        *(float4*)&out[base + (size_t)j * NC + cg * 8] = o0;
        *(float4*)&out[base + (size_t)j * NC + cg * 8 + 4] = o1;
    }
}

// ---------------- Eq2to0 head + output MLP ----------------
__global__ __launch_bounds__(128) void k_final(
    const float* __restrict__ rsum, const float* __restrict__ diag,
    const float* __restrict__ w20, const float* __restrict__ b20,
    const float* __restrict__ wmlp, const float* __restrict__ bmlp,
    float* __restrict__ outp)
{
    int b = blockIdx.x;
    int c = threadIdx.x;
    __shared__ float agg0[NC], agg1[NC], act3[NC];
    float dgv = 0.f, tot = 0.f;
    for (int i = 0; i < NN; ++i) {
        dgv += diag[(size_t)(b * NN + i) * NC + c];
        tot += rsum[(size_t)(b * NN + i) * NC + c];
    }
    agg0[c] = lrelu(dgv / AVGF);
    agg1[c] = lrelu(tot / AVGF);
    __syncthreads();
    float a3 = b20[c];
    for (int k = 0; k < NC; ++k)
        a3 += agg0[k] * w20[k * NC + c] + agg1[k] * w20[(NC + k) * NC + c];
    act3[c] = a3;
    __syncthreads();
    if (c < 2) {
        float o = bmlp[c];
        for (int d = 0; d < NC; ++d) o += act3[d] * wmlp[d * 2 + c];
        outp[b * 2 + c] = o;
    }
}

extern "C" void kernel_launch(void* const* d_in, const int* in_sizes, int n_in,
                              void* d_out, int out_size, void* d_ws, size_t ws_size,
                              hipStream_t stream)
{
    const float* momenta = (const float*)d_in[0];
    const float* scalars = (const float*)d_in[1];
    const int*   nobj    = (const int*)d_in[2];
    const float* w_lin   = (const float*)d_in[3];
    const float* alpha   = (const float*)d_in[4];
    const float* w_in    = (const float*)d_in[5];
    const float* b_in    = (const float*)d_in[6];
    const float *msgW[4], *msgB[4], *eqW[4], *eqB[4], *eqBd[4];
    const float *wm0, *bm0, *w20, *b20, *wmlp, *bmlp;
    if (n_in >= 33) {
        for (int l = 0; l < 4; ++l) {
            msgW[l] = (const float*)d_in[7 + l];
            msgB[l] = (const float*)d_in[11 + l];
            eqW[l]  = (const float*)d_in[15 + l];
            eqB[l]  = (const float*)d_in[19 + l];
            eqBd[l] = (const float*)d_in[23 + l];
        }
        wm0  = (const float*)d_in[27]; bm0  = (const float*)d_in[28];
        w20  = (const float*)d_in[29]; b20  = (const float*)d_in[30];
        wmlp = (const float*)d_in[31]; bmlp = (const float*)d_in[32];
    } else {  // tuples concatenated into one array each
        for (int l = 0; l < 4; ++l) {
            msgW[l] = (const float*)d_in[7] + (size_t)l * NC * NC;
            msgB[l] = (const float*)d_in[8] + l * NC;
            eqW[l]  = (const float*)d_in[9] + (size_t)l * 15 * NC * NC;
            eqB[l]  = (const float*)d_in[10] + l * NC;
            eqBd[l] = (const float*)d_in[11] + l * NC;
        }
        wm0  = (const float*)d_in[12]; bm0  = (const float*)d_in[13];
        w20  = (const float*)d_in[14]; b20  = (const float*)d_in[15];
        wmlp = (const float*)d_in[16]; bmlp = (const float*)d_in[17];
    }

    float* ws = (float*)d_ws;
    const size_t TN = (size_t)NB * NN * NN * NC;  // 16,777,216 floats
    float* T    = ws;
    float* U    = ws + TN;
    float* rsum = ws + 2 * TN;
    float* csum = rsum + (size_t)NB * NN * NC;
    float* diag = csum + (size_t)NB * NN * NC;
    float* Aa   = diag + (size_t)NB * NN * NC;
    float* Bb   = Aa + (size_t)NB * NN * NC;
    float* Dg   = Bb + (size_t)NB * NN * NC;
    float* G    = Dg + (size_t)NB * NN * NC;
    float* Gd   = G + NB * NC;
    float* mask1 = Gd + NB * NC;
    float* P0   = mask1 + NB * NN;
    float* P1   = P0 + (size_t)NB * NN * NCS;
    float* P2   = P1 + (size_t)NB * NN * NCS;
    float* Ps3  = P2 + (size_t)NB * NN * NCS;
    float* Ps4  = Ps3 + NB * NCS;
    size_t need = (size_t)(Ps4 + NB * NCS - ws) * sizeof(float);
    if (ws_size < need) return;  // workspace too small: fail loudly via wrong output

    k_prep<<<NB, 256, 0, stream>>>(scalars, nobj, w_in, mask1, P0, P1, P2, Ps3, Ps4);
    k_build<<<NB * NN, 256, 0, stream>>>(momenta, mask1, P0, P1, P2, Ps3, Ps4,
                                         b_in, w_lin, alpha, T);
    for (int l = 0; l < 4; ++l) {
        k_msg<<<NB * NN, 256, 0, stream>>>(T, msgW[l], msgB[l], mask1, U);
        k_red1<<<NB * NN, 128, 0, stream>>>(U, rsum, csum, diag);
        k_red2<<<NB, 128, 0, stream>>>(rsum, diag, eqW[l], eqB[l], eqBd[l], G, Gd);
        k_red3<<<NB * NN / 8, 256, 0, stream>>>(rsum, csum, diag, eqW[l], Aa, Bb, Dg);
        k_eq_main<<<NB * NN, 256, 0, stream>>>(U, eqW[l], eqW[l] + NC * NC,
                                               Aa, Bb, Dg, G, Gd, mask1, T);
    }
    k_msg<<<NB * NN, 256, 0, stream>>>(T, wm0, bm0, mask1, U);
    k_red1<<<NB * NN, 128, 0, stream>>>(U, rsum, csum, diag);
    k_final<<<NB, 128, 0, stream>>>(rsum, diag, w20, b20, wmlp, bmlp, (float*)d_out);
}

// Round 2
// 1043.380 us; speedup vs baseline: 1.5712x; 1.5712x over previous
//
#include <hip/hip_runtime.h>
#include <math.h>

#define NB 32
#define NN 64
#define NS 9
#define NCS 32
#define NC 128
#define AVGF 49.0f

typedef __attribute__((ext_vector_type(8))) short bf16x8;
typedef __attribute__((ext_vector_type(4))) float f32x4;

__device__ __forceinline__ float lrelu(float x) { return x > 0.0f ? x : 0.01f * x; }

__device__ __forceinline__ unsigned short f2bf(float x) {
    unsigned u = __float_as_uint(x);
    return (unsigned short)((u + 0x7FFF + ((u >> 16) & 1)) >> 16);
}

// ---------------- split weights: W[k][c] fp32 -> Wt_hi/Wt_lo [c][k] bf16 ----------------
__global__ __launch_bounds__(256) void k_split(
    const float* __restrict__ m0, const float* __restrict__ m1,
    const float* __restrict__ m2, const float* __restrict__ m3,
    const float* __restrict__ m4, const float* __restrict__ e0,
    const float* __restrict__ e1, const float* __restrict__ e2,
    const float* __restrict__ e3, short* __restrict__ outbuf)
{
    int m = blockIdx.y;
    const float* src;
    if (m < 5) src = (m == 0 ? m0 : m == 1 ? m1 : m == 2 ? m2 : m == 3 ? m3 : m4);
    else {
        int l = (m - 5) >> 1, sub = (m - 5) & 1;
        const float* e = (l == 0 ? e0 : l == 1 ? e1 : l == 2 ? e2 : e3);
        src = e + sub * NC * NC;
    }
    int idx = blockIdx.x * 256 + threadIdx.x;   // 16384 total
    int k = idx >> 7, c = idx & 127;
    float x = src[idx];
    unsigned short hh = f2bf(x);
    float r = x - __uint_as_float((unsigned)hh << 16);
    unsigned short ll = f2bf(r);
    short* oh = outbuf + (size_t)m * 32768;
    oh[c * NC + k] = (short)hh;
    oh[16384 + c * NC + k] = (short)ll;
}

// ---------------- prep: mask1, eq1to2 projections ----------------
__global__ __launch_bounds__(256) void k_prep(
    const float* __restrict__ scalars, const int* __restrict__ nobj,
    const float* __restrict__ w_in,
    float* __restrict__ mask1, float* __restrict__ P0,
    float* __restrict__ P1, float* __restrict__ P2,
    float* __restrict__ Ps3, float* __restrict__ Ps4)
{
    int b = blockIdx.x, tid = threadIdx.x;
    __shared__ float xs[NN][NS];
    __shared__ float ss[NS];
    int cnt = nobj[b];
    for (int idx = tid; idx < NN * NS; idx += 256) {
        int i = idx / NS, s = idx - i * NS;
        xs[i][s] = (i < cnt) ? scalars[(b * NN + i) * NS + s] : 0.0f;
    }
    if (tid < NN) mask1[b * NN + tid] = (tid < cnt) ? 1.0f : 0.0f;
    __syncthreads();
    if (tid < NS) {
        float a = 0.f;
        for (int i = 0; i < NN; ++i) a += xs[i][tid];
        ss[tid] = a / AVGF;
    }
    __syncthreads();
    for (int idx = tid; idx < NN * NCS; idx += 256) {
        int i = idx >> 5, d = idx & 31;
        float a0 = 0.f, a1 = 0.f, a2 = 0.f;
        #pragma unroll
        for (int s = 0; s < NS; ++s) {
            float x = xs[i][s];
            a0 += x * w_in[(0 * NS + s) * NCS + d];
            a1 += x * w_in[(1 * NS + s) * NCS + d];
            a2 += x * w_in[(2 * NS + s) * NCS + d];
        }
        P0[(b * NN + i) * NCS + d] = a0;
        P1[(b * NN + i) * NCS + d] = a1;
        P2[(b * NN + i) * NCS + d] = a2;
    }
    if (tid < NCS) {
        float a3 = 0.f, a4 = 0.f;
        #pragma unroll
        for (int s = 0; s < NS; ++s) {
            a3 += ss[s] * w_in[(3 * NS + s) * NCS + tid];
            a4 += ss[s] * w_in[(4 * NS + s) * NCS + tid];
        }
        Ps3[b * NCS + tid] = a3;
        Ps4[b * NCS + tid] = a4;
    }
}

// ---------------- build T0 ----------------
__global__ __launch_bounds__(256) void k_build(
    const float* __restrict__ momenta, const float* __restrict__ mask1,
    const float* __restrict__ P0, const float* __restrict__ P1,
    const float* __restrict__ P2, const float* __restrict__ Ps3,
    const float* __restrict__ Ps4, const float* __restrict__ b_in,
    const float* __restrict__ w_lin, const float* __restrict__ alpha,
    float* __restrict__ T)
{
    int blk = blockIdx.x;
    int b = blk >> 6, i = blk & 63;
    int tid = threadIdx.x;
    __shared__ float dots[NN];
    __shared__ float mj[NN];
    if (tid < NN) {
        int j = tid;
        const float* pi = momenta + (size_t)(b * NN + i) * 4;
        const float* pj = momenta + (size_t)(b * NN + j) * 4;
        dots[j] = pi[0] * pj[0] - pi[1] * pj[1] - pi[2] * pj[2] - pi[3] * pj[3];
        mj[j] = mask1[b * NN + j];
    }
    __syncthreads();
    float mi = mask1[b * NN + i];
    for (int idx = tid; idx < NN * NC; idx += 256) {
        int j = idx >> 7, c = idx & 127;
        float m2 = mi * mj[j];
        float v;
        if (c < NCS) {
            v = P0[(b * NN + i) * NCS + c] + P1[(b * NN + j) * NCS + c]
              + Ps3[b * NCS + c] + b_in[c];
            if (i == j) v += P2[(b * NN + i) * NCS + c] + Ps4[b * NCS + c];
            v = lrelu(v) * m2;
        } else {
            int c2 = c - NCS;
            float r = dots[j] * w_lin[c2];
            v = alpha[c2] * copysignf(log1pf(fabsf(r)), r) * m2;
        }
        T[(size_t)blk * NN * NC + idx] = v;
    }
}

// ---------------- MessageNet via bf16x3 MFMA ----------------
// block: 128 consecutive M-rows (2 (b,i) pairs); 4 waves, wave w -> cols w*32..+32
__global__ __launch_bounds__(256) void k_msg_mfma(
    const float* __restrict__ in, const short* __restrict__ Wh,
    const short* __restrict__ Wl, const float* __restrict__ bias,
    const float* __restrict__ mask1, float* __restrict__ out)
{
    __shared__ __align__(16) char smem[128 * 132 * 4];
    short* Ah = (short*)smem;           // [128][128] bf16 hi, 16B-slot swizzled
    short* Al = Ah + 16384;
    float* Ls = (float*)smem;           // [128][132] epilogue staging
    int tid = threadIdx.x;
    size_t R0 = (size_t)blockIdx.x * 128;

    #pragma unroll
    for (int it = 0; it < 8; ++it) {
        int sid = tid + it * 256;
        int row = sid >> 4, ks = sid & 15;
        const float* src = in + (R0 + row) * NC + ks * 8;
        float4 f0 = *(const float4*)src;
        float4 f1 = *(const float4*)(src + 4);
        float v[8] = {f0.x, f0.y, f0.z, f0.w, f1.x, f1.y, f1.z, f1.w};
        bf16x8 hv, lv;
        #pragma unroll
        for (int q = 0; q < 8; ++q) {
            unsigned short hh = f2bf(v[q]);
            hv[q] = (short)hh;
            lv[q] = (short)f2bf(v[q] - __uint_as_float((unsigned)hh << 16));
        }
        int slot = ks ^ (row & 7);
        *(bf16x8*)&Ah[row * 128 + slot * 8] = hv;
        *(bf16x8*)&Al[row * 128 + slot * 8] = lv;
    }
    __syncthreads();

    int w = tid >> 6, l = tid & 63;
    int lr = l & 15, lk = l >> 4;
    f32x4 acc[8][2];
    #pragma unroll
    for (int mt = 0; mt < 8; ++mt) { acc[mt][0] = (f32x4)0.f; acc[mt][1] = (f32x4)0.f; }
    const short* WhB = Wh + (w * 32 + lr) * NC + lk * 8;
    const short* WlB = Wl + (w * 32 + lr) * NC + lk * 8;
    #pragma unroll
    for (int kt = 0; kt < 4; ++kt) {
        bf16x8 bh0 = *(const bf16x8*)&WhB[kt * 32];
        bf16x8 bl0 = *(const bf16x8*)&WlB[kt * 32];
        bf16x8 bh1 = *(const bf16x8*)&WhB[16 * NC + kt * 32];
        bf16x8 bl1 = *(const bf16x8*)&WlB[16 * NC + kt * 32];
        #pragma unroll
        for (int mt = 0; mt < 8; ++mt) {
            int row = mt * 16 + lr;
            int slot = (kt * 4 + lk) ^ (row & 7);
            bf16x8 ah = *(const bf16x8*)&Ah[row * 128 + slot * 8];
            bf16x8 al = *(const bf16x8*)&Al[row * 128 + slot * 8];
            acc[mt][0] = __builtin_amdgcn_mfma_f32_16x16x32_bf16(ah, bh0, acc[mt][0], 0, 0, 0);
            acc[mt][0] = __builtin_amdgcn_mfma_f32_16x16x32_bf16(ah, bl0, acc[mt][0], 0, 0, 0);
            acc[mt][0] = __builtin_amdgcn_mfma_f32_16x16x32_bf16(al, bh0, acc[mt][0], 0, 0, 0);
            acc[mt][1] = __builtin_amdgcn_mfma_f32_16x16x32_bf16(ah, bh1, acc[mt][1], 0, 0, 0);
            acc[mt][1] = __builtin_amdgcn_mfma_f32_16x16x32_bf16(ah, bl1, acc[mt][1], 0, 0, 0);
            acc[mt][1] = __builtin_amdgcn_mfma_f32_16x16x32_bf16(al, bh1, acc[mt][1], 0, 0, 0);
        }
    }
    __syncthreads();
    #pragma unroll
    for (int mt = 0; mt < 8; ++mt)
        #pragma unroll
        for (int nt = 0; nt < 2; ++nt)
            #pragma unroll
            for (int q = 0; q < 4; ++q)
                Ls[(mt * 16 + lk * 4 + q) * 132 + w * 32 + nt * 16 + lr] = acc[mt][nt][q];
    __syncthreads();
    #pragma unroll
    for (int it = 0; it < 8; ++it) {
        int sid = tid + it * 256;
        int row = sid >> 4, ks = sid & 15;
        size_t gr = R0 + row;
        int b = (int)(gr >> 12), ij = (int)(gr & 4095);
        float m2 = mask1[b * 64 + (ij >> 6)] * mask1[b * 64 + (ij & 63)];
        float4 o0, o1;
        float o[8];
        #pragma unroll
        for (int q = 0; q < 8; ++q) {
            float v = Ls[row * 132 + ks * 8 + q] + bias[ks * 8 + q];
            o[q] = lrelu(v) * m2;
        }
        o0 = make_float4(o[0], o[1], o[2], o[3]);
        o1 = make_float4(o[4], o[5], o[6], o[7]);
        *(float4*)&out[gr * NC + ks * 8] = o0;
        *(float4*)&out[gr * NC + ks * 8 + 4] = o1;
    }
}

// ---------------- eq2to2 main via bf16x3 MFMA ----------------
// block: one (b,i); M = 64 j-rows; U@W0 + U^T@W1 + broadcast terms
__global__ __launch_bounds__(256) void k_eq_mfma(
    const float* __restrict__ U, const short* __restrict__ W0h,
    const short* __restrict__ W0l, const short* __restrict__ W1h,
    const short* __restrict__ W1l, const float* __restrict__ A,
    const float* __restrict__ Bc, const float* __restrict__ Dg,
    const float* __restrict__ G, const float* __restrict__ Gd,
    const float* __restrict__ mask1, float* __restrict__ out)
{
    __shared__ __align__(16) char smem[65536];
    short* A1h = (short*)smem;          // [64][128] U rows (j,k)
    short* A1l = A1h + 8192;
    short* A2h = A1l + 8192;            // [64][128] U^T rows
    short* A2l = A2h + 8192;
    float* Ls = (float*)smem;           // [64][132]
    int tid = threadIdx.x;
    int blk = blockIdx.x;
    int b = blk >> 6, i = blk & 63;

    #pragma unroll
    for (int it = 0; it < 8; ++it) {
        int sid = tid + it * 256;
        int arr = sid >> 10, rem = sid & 1023;
        int row = rem >> 4, ks = rem & 15;
        size_t grow = arr == 0 ? ((size_t)(b * 64 + i) * 64 + row)
                               : ((size_t)(b * 64 + row) * 64 + i);
        const float* src = U + grow * NC + ks * 8;
        float4 f0 = *(const float4*)src;
        float4 f1 = *(const float4*)(src + 4);
        float v[8] = {f0.x, f0.y, f0.z, f0.w, f1.x, f1.y, f1.z, f1.w};
        bf16x8 hv, lv;
        #pragma unroll
        for (int q = 0; q < 8; ++q) {
            unsigned short hh = f2bf(v[q]);
            hv[q] = (short)hh;
            lv[q] = (short)f2bf(v[q] - __uint_as_float((unsigned)hh << 16));
        }
        int slot = ks ^ (row & 7);
        short* dh = arr == 0 ? A1h : A2h;
        short* dl = arr == 0 ? A1l : A2l;
        *(bf16x8*)&dh[row * 128 + slot * 8] = hv;
        *(bf16x8*)&dl[row * 128 + slot * 8] = lv;
    }
    __syncthreads();

    int w = tid >> 6, l = tid & 63;
    int lr = l & 15, lk = l >> 4;
    f32x4 acc[4][2];
    #pragma unroll
    for (int mt = 0; mt < 4; ++mt) { acc[mt][0] = (f32x4)0.f; acc[mt][1] = (f32x4)0.f; }
    int cb = (w * 32 + lr) * NC + lk * 8;
    const short* W0hB = W0h + cb;
    const short* W0lB = W0l + cb;
    const short* W1hB = W1h + cb;
    const short* W1lB = W1l + cb;
    #pragma unroll
    for (int kt = 0; kt < 4; ++kt) {
        bf16x8 b0h0 = *(const bf16x8*)&W0hB[kt * 32];
        bf16x8 b0l0 = *(const bf16x8*)&W0lB[kt * 32];
        bf16x8 b1h0 = *(const bf16x8*)&W1hB[kt * 32];
        bf16x8 b1l0 = *(const bf16x8*)&W1lB[kt * 32];
        bf16x8 b0h1 = *(const bf16x8*)&W0hB[16 * NC + kt * 32];
        bf16x8 b0l1 = *(const bf16x8*)&W0lB[16 * NC + kt * 32];
        bf16x8 b1h1 = *(const bf16x8*)&W1hB[16 * NC + kt * 32];
        bf16x8 b1l1 = *(const bf16x8*)&W1lB[16 * NC + kt * 32];
        #pragma unroll
        for (int mt = 0; mt < 4; ++mt) {
            int row = mt * 16 + lr;
            int slot = (kt * 4 + lk) ^ (row & 7);
            bf16x8 a1h = *(const bf16x8*)&A1h[row * 128 + slot * 8];
            bf16x8 a1l = *(const bf16x8*)&A1l[row * 128 + slot * 8];
            bf16x8 a2h = *(const bf16x8*)&A2h[row * 128 + slot * 8];
            bf16x8 a2l = *(const bf16x8*)&A2l[row * 128 + slot * 8];
            acc[mt][0] = __builtin_amdgcn_mfma_f32_16x16x32_bf16(a1h, b0h0, acc[mt][0], 0, 0, 0);
            acc[mt][0] = __builtin_amdgcn_mfma_f32_16x16x32_bf16(a1h, b0l0, acc[mt][0], 0, 0, 0);
            acc[mt][0] = __builtin_amdgcn_mfma_f32_16x16x32_bf16(a1l, b0h0, acc[mt][0], 0, 0, 0);
            acc[mt][0] = __builtin_amdgcn_mfma_f32_16x16x32_bf16(a2h, b1h0, acc[mt][0], 0, 0, 0);
            acc[mt][0] = __builtin_amdgcn_mfma_f32_16x16x32_bf16(a2h, b1l0, acc[mt][0], 0, 0, 0);
            acc[mt][0] = __builtin_amdgcn_mfma_f32_16x16x32_bf16(a2l, b1h0, acc[mt][0], 0, 0, 0);
            acc[mt][1] = __builtin_amdgcn_mfma_f32_16x16x32_bf16(a1h, b0h1, acc[mt][1], 0, 0, 0);
            acc[mt][1] = __builtin_amdgcn_mfma_f32_16x16x32_bf16(a1h, b0l1, acc[mt][1], 0, 0, 0);
            acc[mt][1] = __builtin_amdgcn_mfma_f32_16x16x32_bf16(a1l, b0h1, acc[mt][1], 0, 0, 0);
            acc[mt][1] = __builtin_amdgcn_mfma_f32_16x16x32_bf16(a2h, b1h1, acc[mt][1], 0, 0, 0);
            acc[mt][1] = __builtin_amdgcn_mfma_f32_16x16x32_bf16(a2h, b1l1, acc[mt][1], 0, 0, 0);
            acc[mt][1] = __builtin_amdgcn_mfma_f32_16x16x32_bf16(a2l, b1h1, acc[mt][1], 0, 0, 0);
        }
    }
    __syncthreads();
    #pragma unroll
    for (int mt = 0; mt < 4; ++mt)
        #pragma unroll
        for (int nt = 0; nt < 2; ++nt)
            #pragma unroll
            for (int q = 0; q < 4; ++q)
                Ls[(mt * 16 + lk * 4 + q) * 132 + w * 32 + nt * 16 + lr] = acc[mt][nt][q];
    __syncthreads();

    float mi = mask1[b * 64 + i];
    const float* Ai  = A  + (size_t)(b * 64 + i) * NC;
    const float* Gb  = G  + (size_t)b * NC;
    const float* Dgi = Dg + (size_t)(b * 64 + i) * NC;
    const float* Gdb = Gd + (size_t)b * NC;
    #pragma unroll
    for (int it = 0; it < 4; ++it) {
        int sid = tid + it * 256;
        int row = sid >> 4, ks = sid & 15;
        float m2 = mi * mask1[b * 64 + row];
        const float* Bj = Bc + (size_t)(b * 64 + row) * NC;
        float o[8];
        #pragma unroll
        for (int q = 0; q < 8; ++q) {
            int c = ks * 8 + q;
            float v = Ls[row * 132 + c] + Ai[c] + Bj[c] + Gb[c];
            if (row == i) v += Dgi[c] + Gdb[c];
            o[q] = lrelu(v) * m2;
        }
        size_t obase = ((size_t)(b * 64 + i) * 64 + row) * NC + ks * 8;
        *(float4*)&out[obase] = make_float4(o[0], o[1], o[2], o[3]);
        *(float4*)&out[obase + 4] = make_float4(o[4], o[5], o[6], o[7]);
    }
}

// ---------------- reductions: row sums, col sums, diag ----------------
__global__ __launch_bounds__(128) void k_red1(
    const float* __restrict__ U, float* __restrict__ rsum,
    float* __restrict__ csum, float* __restrict__ diag)
{
    int blk = blockIdx.x;
    int b = blk >> 6, i = blk & 63;
    int c = threadIdx.x;
    const float* Ub = U + (size_t)b * NN * NN * NC;
    float rs = 0.f, cs = 0.f;
    for (int j = 0; j < NN; ++j) {
        rs += Ub[((size_t)i * NN + j) * NC + c];
        cs += Ub[((size_t)j * NN + i) * NC + c];
    }
    rsum[(size_t)blk * NC + c] = rs / AVGF;
    csum[(size_t)blk * NC + c] = cs / AVGF;
    diag[(size_t)blk * NC + c] = Ub[((size_t)i * NN + i) * NC + c];
}

__global__ __launch_bounds__(128) void k_red2(
    const float* __restrict__ rsum, const float* __restrict__ diag,
    const float* __restrict__ Weq, const float* __restrict__ eqb,
    const float* __restrict__ eqbd, float* __restrict__ G, float* __restrict__ Gd)
{
    int b = blockIdx.x;
    int c = threadIdx.x;
    __shared__ float ts[NC], trs[NC];
    float tt = 0.f, rr = 0.f;
    for (int i = 0; i < NN; ++i) {
        tt += rsum[(size_t)(b * NN + i) * NC + c];
        rr += diag[(size_t)(b * NN + i) * NC + c];
    }
    ts[c] = tt / AVGF;
    trs[c] = rr / AVGF;
    __syncthreads();
    float g = eqb[c], gd = eqbd[c];
    for (int k = 0; k < NC; ++k) {
        float tv = ts[k], rv = trs[k];
        g  += tv * Weq[(11 * NC + k) * NC + c] + rv * Weq[(13 * NC + k) * NC + c];
        gd += tv * Weq[(12 * NC + k) * NC + c] + rv * Weq[(14 * NC + k) * NC + c];
    }
    G[b * NC + c] = g;
    Gd[b * NC + c] = gd;
}

__global__ __launch_bounds__(256) void k_red3(
    const float* __restrict__ rsum, const float* __restrict__ csum,
    const float* __restrict__ diag, const float* __restrict__ Weq,
    float* __restrict__ A, float* __restrict__ Bc, float* __restrict__ Dg)
{
    int blk = blockIdx.x;
    int row0 = blk * 8;
    int tid = threadIdx.x;
    int c = tid & 127, half = tid >> 7;
    __shared__ float ds[8][NC], rs[8][NC], cs[8][NC];
    for (int idx = tid; idx < 8 * NC; idx += 256) {
        int r = idx >> 7, cc = idx & 127;
        ds[r][cc] = diag[(size_t)(row0 + r) * NC + cc];
        rs[r][cc] = rsum[(size_t)(row0 + r) * NC + cc];
        cs[r][cc] = csum[(size_t)(row0 + r) * NC + cc];
    }
    __syncthreads();
    float aA[4] = {0, 0, 0, 0}, aB[4] = {0, 0, 0, 0}, aD[4] = {0, 0, 0, 0};
    for (int k = 0; k < NC; ++k) {
        float w2  = Weq[(2  * NC + k) * NC + c];
        float w3  = Weq[(3  * NC + k) * NC + c];
        float w4  = Weq[(4  * NC + k) * NC + c];
        float w5  = Weq[(5  * NC + k) * NC + c];
        float w6  = Weq[(6  * NC + k) * NC + c];
        float w7  = Weq[(7  * NC + k) * NC + c];
        float w8  = Weq[(8  * NC + k) * NC + c];
        float w9  = Weq[(9  * NC + k) * NC + c];
        float w10 = Weq[(10 * NC + k) * NC + c];
        #pragma unroll
        for (int r = 0; r < 4; ++r) {
            int rr = half * 4 + r;
            float dv = ds[rr][k], rv = rs[rr][k], cv = cs[rr][k];
            aA[r] += dv * w3 + rv * w5 + cv * w7;
            aB[r] += dv * w4 + rv * w6 + cv * w8;
            aD[r] += dv * w2 + rv * w9 + cv * w10;
        }
    }
    #pragma unroll
    for (int r = 0; r < 4; ++r) {
        size_t o = (size_t)(row0 + half * 4 + r) * NC + c;
        A[o] = aA[r];
        Bc[o] = aB[r];
        Dg[o] = aD[r];
    }
}

__global__ __launch_bounds__(128) void k_final(
    const float* __restrict__ rsum, const float* __restrict__ diag,
    const float* __restrict__ w20, const float* __restrict__ b20,
    const float* __restrict__ wmlp, const float* __restrict__ bmlp,
    float* __restrict__ outp)
{
    int b = blockIdx.x;
    int c = threadIdx.x;
    __shared__ float agg0[NC], agg1[NC], act3[NC];
    float dgv = 0.f, tot = 0.f;
    for (int i = 0; i < NN; ++i) {
        dgv += diag[(size_t)(b * NN + i) * NC + c];
        tot += rsum[(size_t)(b * NN + i) * NC + c];
    }
    agg0[c] = lrelu(dgv / AVGF);
    agg1[c] = lrelu(tot / AVGF);
    __syncthreads();
    float a3 = b20[c];
    for (int k = 0; k < NC; ++k)
        a3 += agg0[k] * w20[k * NC + c] + agg1[k] * w20[(NC + k) * NC + c];
    act3[c] = a3;
    __syncthreads();
    if (c < 2) {
        float o = bmlp[c];
        for (int d = 0; d < NC; ++d) o += act3[d] * wmlp[d * 2 + c];
        outp[b * 2 + c] = o;
    }
}

extern "C" void kernel_launch(void* const* d_in, const int* in_sizes, int n_in,
                              void* d_out, int out_size, void* d_ws, size_t ws_size,
                              hipStream_t stream)
{
    const float* momenta = (const float*)d_in[0];
    const float* scalars = (const float*)d_in[1];
    const int*   nobj    = (const int*)d_in[2];
    const float* w_lin   = (const float*)d_in[3];
    const float* alpha   = (const float*)d_in[4];
    const float* w_in    = (const float*)d_in[5];
    const float* b_in    = (const float*)d_in[6];
    const float *msgW[4], *msgB[4], *eqW[4], *eqB[4], *eqBd[4];
    const float *wm0, *bm0, *w20, *b20, *wmlp, *bmlp;
    if (n_in >= 33) {
        for (int l = 0; l < 4; ++l) {
            msgW[l] = (const float*)d_in[7 + l];
            msgB[l] = (const float*)d_in[11 + l];
            eqW[l]  = (const float*)d_in[15 + l];
            eqB[l]  = (const float*)d_in[19 + l];
            eqBd[l] = (const float*)d_in[23 + l];
        }
        wm0  = (const float*)d_in[27]; bm0  = (const float*)d_in[28];
        w20  = (const float*)d_in[29]; b20  = (const float*)d_in[30];
        wmlp = (const float*)d_in[31]; bmlp = (const float*)d_in[32];
    } else {
        for (int l = 0; l < 4; ++l) {
            msgW[l] = (const float*)d_in[7] + (size_t)l * NC * NC;
            msgB[l] = (const float*)d_in[8] + l * NC;
            eqW[l]  = (const float*)d_in[9] + (size_t)l * 15 * NC * NC;
            eqB[l]  = (const float*)d_in[10] + l * NC;
            eqBd[l] = (const float*)d_in[11] + l * NC;
        }
        wm0  = (const float*)d_in[12]; bm0  = (const float*)d_in[13];
        w20  = (const float*)d_in[14]; b20  = (const float*)d_in[15];
        wmlp = (const float*)d_in[16]; bmlp = (const float*)d_in[17];
    }

    float* ws = (float*)d_ws;
    const size_t TN = (size_t)NB * NN * NN * NC;  // 16,777,216 floats
    float* T    = ws;
    float* U    = ws + TN;
    float* rsum = ws + 2 * TN;
    float* csum = rsum + (size_t)NB * NN * NC;
    float* diag = csum + (size_t)NB * NN * NC;
    float* Aa   = diag + (size_t)NB * NN * NC;
    float* Bb   = Aa + (size_t)NB * NN * NC;
    float* Dg   = Bb + (size_t)NB * NN * NC;
    float* G    = Dg + (size_t)NB * NN * NC;
    float* Gd   = G + NB * NC;
    float* mask1 = Gd + NB * NC;
    float* P0   = mask1 + NB * NN;
    float* P1   = P0 + (size_t)NB * NN * NCS;
    float* P2   = P1 + (size_t)NB * NN * NCS;
    float* Ps3  = P2 + (size_t)NB * NN * NCS;
    float* Ps4  = Ps3 + NB * NCS;
    float* endf = Ps4 + NB * NCS;
    // align split-weight buffer to 16B
    short* SW = (short*)(((uintptr_t)endf + 15) & ~(uintptr_t)15);
    size_t need = ((char*)(SW + 13 * 32768)) - (char*)d_ws;
    if (ws_size < need) return;

    k_split<<<dim3(64, 13), 256, 0, stream>>>(msgW[0], msgW[1], msgW[2], msgW[3],
                                              wm0, eqW[0], eqW[1], eqW[2], eqW[3], SW);
    k_prep<<<NB, 256, 0, stream>>>(scalars, nobj, w_in, mask1, P0, P1, P2, Ps3, Ps4);
    k_build<<<NB * NN, 256, 0, stream>>>(momenta, mask1, P0, P1, P2, Ps3, Ps4,
                                         b_in, w_lin, alpha, T);
    for (int l = 0; l < 4; ++l) {
        short* Wm = SW + (size_t)l * 32768;
        k_msg_mfma<<<NB * NN * NN / 128, 256, 0, stream>>>(T, Wm, Wm + 16384,
                                                           msgB[l], mask1, U);
        k_red1<<<NB * NN, 128, 0, stream>>>(U, rsum, csum, diag);
        k_red2<<<NB, 128, 0, stream>>>(rsum, diag, eqW[l], eqB[l], eqBd[l], G, Gd);
        k_red3<<<NB * NN / 8, 256, 0, stream>>>(rsum, csum, diag, eqW[l], Aa, Bb, Dg);
        short* W0 = SW + (size_t)(5 + 2 * l) * 32768;
        short* W1 = SW + (size_t)(6 + 2 * l) * 32768;
        k_eq_mfma<<<NB * NN, 256, 0, stream>>>(U, W0, W0 + 16384, W1, W1 + 16384,
                                               Aa, Bb, Dg, G, Gd, mask1, T);
    }
    short* Wm0 = SW + (size_t)4 * 32768;
    k_msg_mfma<<<NB * NN * NN / 128, 256, 0, stream>>>(T, Wm0, Wm0 + 16384,
                                                       bm0, mask1, U);
    k_red1<<<NB * NN, 128, 0, stream>>>(U, rsum, csum, diag);
    k_final<<<NB, 128, 0, stream>>>(rsum, diag, w20, b20, wmlp, bmlp, (float*)d_out);
}

// Round 3
// 931.623 us; speedup vs baseline: 1.7597x; 1.1200x over previous
//
#include <hip/hip_runtime.h>
#include <math.h>

#define NB 32
#define NN 64
#define NS 9
#define NCS 32
#define NC 128
#define AVGF 49.0f
#define TILE 8192   // shorts per (b,i) tile: 64 rows x 128 ch

typedef __attribute__((ext_vector_type(8))) short bf16x8;
typedef __attribute__((ext_vector_type(4))) float f32x4;

#define MFMA(a,bb,c) c = __builtin_amdgcn_mfma_f32_16x16x32_bf16(a,bb,c,0,0,0)

__device__ __forceinline__ float lrelu(float x){ return x>0.f ? x : 0.01f*x; }
__device__ __forceinline__ unsigned short f2bf(float x){
    unsigned u=__float_as_uint(x);
    return (unsigned short)((u + 0x7FFF + ((u>>16)&1)) >> 16);
}
__device__ __forceinline__ float bf2f(unsigned short h){ return __uint_as_float(((unsigned)h)<<16); }
// XCD-affinity map: batch pinned to xcd = wgid%8 (4 batches/XCD, 64 blocks contiguous)
__device__ __forceinline__ void map_bi(int wg,int&b,int&i){ int x=wg&7,q=wg>>3; b=x*4+(q>>6); i=q&63; }

// ---------------- split weights: W[k][c] fp32 -> [c][k] bf16 hi/lo ----------------
__global__ __launch_bounds__(256) void k_split(
    const float* __restrict__ m0, const float* __restrict__ m1,
    const float* __restrict__ m2, const float* __restrict__ m3,
    const float* __restrict__ m4, const float* __restrict__ e0,
    const float* __restrict__ e1, const float* __restrict__ e2,
    const float* __restrict__ e3, short* __restrict__ outbuf)
{
    int m = blockIdx.y;
    const float* src;
    if (m < 5) src = (m == 0 ? m0 : m == 1 ? m1 : m == 2 ? m2 : m == 3 ? m3 : m4);
    else {
        int l = (m - 5) >> 1, sub = (m - 5) & 1;
        const float* e = (l == 0 ? e0 : l == 1 ? e1 : l == 2 ? e2 : e3);
        src = e + sub * NC * NC;
    }
    int idx = blockIdx.x * 256 + threadIdx.x;
    int k = idx >> 7, c = idx & 127;
    float x = src[idx];
    unsigned short hh = f2bf(x);
    unsigned short ll = f2bf(x - bf2f(hh));
    short* oh = outbuf + (size_t)m * 32768;
    oh[c * NC + k] = (short)hh;
    oh[16384 + c * NC + k] = (short)ll;
}

// ---------------- prep: mask1, eq1to2 projections ----------------
__global__ __launch_bounds__(256) void k_prep(
    const float* __restrict__ scalars, const int* __restrict__ nobj,
    const float* __restrict__ w_in,
    float* __restrict__ mask1, float* __restrict__ P0,
    float* __restrict__ P1, float* __restrict__ P2,
    float* __restrict__ Ps3, float* __restrict__ Ps4)
{
    int b = blockIdx.x, tid = threadIdx.x;
    __shared__ float xs[NN][NS];
    __shared__ float ss[NS];
    int cnt = nobj[b];
    for (int idx = tid; idx < NN * NS; idx += 256) {
        int i = idx / NS, s = idx - i * NS;
        xs[i][s] = (i < cnt) ? scalars[(b * NN + i) * NS + s] : 0.0f;
    }
    if (tid < NN) mask1[b * NN + tid] = (tid < cnt) ? 1.0f : 0.0f;
    __syncthreads();
    if (tid < NS) {
        float a = 0.f;
        for (int i = 0; i < NN; ++i) a += xs[i][tid];
        ss[tid] = a / AVGF;
    }
    __syncthreads();
    for (int idx = tid; idx < NN * NCS; idx += 256) {
        int i = idx >> 5, d = idx & 31;
        float a0 = 0.f, a1 = 0.f, a2 = 0.f;
        #pragma unroll
        for (int s = 0; s < NS; ++s) {
            float x = xs[i][s];
            a0 += x * w_in[(0 * NS + s) * NCS + d];
            a1 += x * w_in[(1 * NS + s) * NCS + d];
            a2 += x * w_in[(2 * NS + s) * NCS + d];
        }
        P0[(b * NN + i) * NCS + d] = a0;
        P1[(b * NN + i) * NCS + d] = a1;
        P2[(b * NN + i) * NCS + d] = a2;
    }
    if (tid < NCS) {
        float a3 = 0.f, a4 = 0.f;
        #pragma unroll
        for (int s = 0; s < NS; ++s) {
            a3 += ss[s] * w_in[(3 * NS + s) * NCS + tid];
            a4 += ss[s] * w_in[(4 * NS + s) * NCS + tid];
        }
        Ps3[b * NCS + tid] = a3;
        Ps4[b * NCS + tid] = a4;
    }
}

// ---------------- F0: build T0 tile in LDS, msg1 MFMA, write U1 tiles + rsum/diag ----------------
__global__ __launch_bounds__(256) void k_f0(
    const float* __restrict__ momenta, const float* __restrict__ mask1,
    const float* __restrict__ P0, const float* __restrict__ P1,
    const float* __restrict__ P2, const float* __restrict__ Ps3,
    const float* __restrict__ Ps4, const float* __restrict__ b_in,
    const float* __restrict__ w_lin, const float* __restrict__ alpha,
    const short* __restrict__ Wh, const short* __restrict__ Wl,
    const float* __restrict__ bias,
    short* __restrict__ Uh, short* __restrict__ Ul,
    float* __restrict__ rsum, float* __restrict__ diag)
{
    __shared__ __align__(16) char smem[43008];
    short* Eh = (short*)smem;                 // [0,16K)
    short* El = Eh + TILE;                    // [16K,32K)
    float* Ls = (float*)smem;                 // overlay [0,32K)
    float* dots = (float*)(smem + 32768);     // 64
    float* mjv  = dots + 64;                  // 64
    float* Ls2  = mjv + 64;                   // [16][128] 8KB
    int tid = threadIdx.x;
    int b, i; map_bi(blockIdx.x, b, i);
    if (tid < NN) {
        const float* pi = momenta + (size_t)(b*NN+i)*4;
        const float* pj = momenta + (size_t)(b*NN+tid)*4;
        dots[tid] = pi[0]*pj[0]-pi[1]*pj[1]-pi[2]*pj[2]-pi[3]*pj[3];
        mjv[tid] = mask1[b*NN+tid];
    }
    __syncthreads();
    float mi = mask1[b*NN+i];
    // build T0 tile -> Eh/El (bf16 hi/lo, swizzled)
    #pragma unroll
    for (int it = 0; it < 4; ++it) {
        int g = tid + it*256, j = g>>4, ks = g&15, c0 = ks*8;
        float m2 = mi * mjv[j];
        float v[8];
        if (ks < 4) {
            const float* p0 = P0 + (size_t)(b*NN+i)*NCS + c0;
            const float* p1 = P1 + (size_t)(b*NN+j)*NCS + c0;
            const float* s3 = Ps3 + b*NCS + c0;
            #pragma unroll
            for (int q = 0; q < 8; ++q) {
                float x = p0[q] + p1[q] + s3[q] + b_in[c0+q];
                if (j == i) x += P2[(size_t)(b*NN+i)*NCS + c0+q] + Ps4[b*NCS + c0+q];
                v[q] = lrelu(x) * m2;
            }
        } else {
            int c2 = c0 - NCS;
            float dj = dots[j];
            #pragma unroll
            for (int q = 0; q < 8; ++q) {
                float r = dj * w_lin[c2+q];
                v[q] = alpha[c2+q] * copysignf(log1pf(fabsf(r)), r) * m2;
            }
        }
        bf16x8 hv, lv;
        #pragma unroll
        for (int q = 0; q < 8; ++q) {
            unsigned short hh = f2bf(v[q]);
            hv[q] = (short)hh;
            lv[q] = (short)f2bf(v[q] - bf2f(hh));
        }
        int slot = (ks ^ (j & 7)) * 8;
        *(bf16x8*)&Eh[j*128 + slot] = hv;
        *(bf16x8*)&El[j*128 + slot] = lv;
    }
    __syncthreads();
    // msg MFMA
    int w = tid>>6, l = tid&63, lr = l&15, lk = l>>4;
    f32x4 acc[4][2];
    #pragma unroll
    for (int mt = 0; mt < 4; ++mt) { acc[mt][0] = (f32x4)0.f; acc[mt][1] = (f32x4)0.f; }
    const int cb = (w*32 + lr)*NC + lk*8;
    #pragma unroll
    for (int kt = 0; kt < 4; ++kt) {
        bf16x8 bh0 = *(const bf16x8*)&Wh[cb + kt*32];
        bf16x8 bl0 = *(const bf16x8*)&Wl[cb + kt*32];
        bf16x8 bh1 = *(const bf16x8*)&Wh[cb + 16*NC + kt*32];
        bf16x8 bl1 = *(const bf16x8*)&Wl[cb + 16*NC + kt*32];
        #pragma unroll
        for (int mt = 0; mt < 4; ++mt) {
            int row = mt*16 + lr;
            int slot = ((kt*4 + lk) ^ (row & 7)) * 8;
            bf16x8 ah = *(const bf16x8*)&Eh[row*128 + slot];
            bf16x8 al = *(const bf16x8*)&El[row*128 + slot];
            MFMA(ah, bh0, acc[mt][0]); MFMA(ah, bl0, acc[mt][0]); MFMA(al, bh0, acc[mt][0]);
            MFMA(ah, bh1, acc[mt][1]); MFMA(ah, bl1, acc[mt][1]); MFMA(al, bh1, acc[mt][1]);
        }
    }
    __syncthreads();
    #pragma unroll
    for (int mt = 0; mt < 4; ++mt)
        #pragma unroll
        for (int nt = 0; nt < 2; ++nt)
            #pragma unroll
            for (int q = 0; q < 4; ++q)
                Ls[(mt*16 + lk*4 + q)*128 + w*32 + nt*16 + lr] = acc[mt][nt][q];
    __syncthreads();
    // epilogue: bias/lrelu/mask -> write U1 tiles, rsum partials, diag
    size_t t0 = (size_t)(b*NN + i) * TILE;
    float pr[8] = {0,0,0,0,0,0,0,0};
    #pragma unroll
    for (int it = 0; it < 4; ++it) {
        int g = tid + it*256, j = g>>4, ks = g&15, c0 = ks*8;
        float m2 = mi * mjv[j];
        bf16x8 hv, lv;
        #pragma unroll
        for (int q = 0; q < 8; ++q) {
            float v = lrelu(Ls[j*128 + c0 + q] + bias[c0+q]) * m2;
            pr[q] += v;
            if (j == i) diag[(size_t)(b*NN+i)*NC + c0 + q] = v;
            unsigned short hh = f2bf(v);
            hv[q] = (short)hh;
            lv[q] = (short)f2bf(v - bf2f(hh));
        }
        int slot = (ks ^ (j & 7)) * 8;
        *(bf16x8*)&Uh[t0 + j*128 + slot] = hv;
        *(bf16x8*)&Ul[t0 + j*128 + slot] = lv;
    }
    #pragma unroll
    for (int q = 0; q < 8; ++q) Ls2[(tid>>4)*128 + (tid&15)*8 + q] = pr[q];
    __syncthreads();
    if (tid < 128) {
        float s = 0.f;
        #pragma unroll
        for (int gb = 0; gb < 16; ++gb) s += Ls2[gb*128 + tid];
        rsum[(size_t)(b*NN+i)*NC + tid] = s / AVGF;
    }
}

// ---------------- F_eq: eq_l (U@W0 + U^T@W1 + broadcasts) fused with msg_{l+1} ----------------
template<int WOUT>
__global__ __launch_bounds__(256) void k_feq(
    const short* __restrict__ Uinh, const short* __restrict__ Uinl,
    const short* __restrict__ W0h, const short* __restrict__ W0l,
    const short* __restrict__ W1h, const short* __restrict__ W1l,
    const short* __restrict__ Wmh, const short* __restrict__ Wml,
    const float* __restrict__ mbias,
    const float* __restrict__ A, const float* __restrict__ Bc,
    const float* __restrict__ Dgv, const float* __restrict__ G,
    const float* __restrict__ Gd, const float* __restrict__ mask1,
    short* __restrict__ Uoh, short* __restrict__ Uol,
    float* __restrict__ rsum, float* __restrict__ diag)
{
    __shared__ __align__(16) char smem[65536];
    short* A1h = (short*)smem;          // [0,16K)
    short* A1l = A1h + TILE;            // [16K,32K)
    short* A2h = A1l + TILE;            // [32K,48K)
    short* A2l = A2h + TILE;            // [48K,64K)
    float* Ls  = (float*)smem;          // overlay [0,32K) (after eq MFMA)
    short* Eh  = A2h;                   // overlay [32K,48K) (after eq MFMA)
    short* El  = A2l;
    float* Ls2 = (float*)(smem + 32768);// overlay [32K,40K) (after msg MFMA)
    int tid = threadIdx.x;
    int b, i; map_bi(blockIdx.x, b, i);
    size_t t0 = (size_t)(b*NN + i) * TILE;
    // row panel: straight tile copy (already MFMA layout)
    #pragma unroll
    for (int it = 0; it < 4; ++it) {
        int g = tid + it*256;
        *(bf16x8*)&A1h[g*8] = *(const bf16x8*)&Uinh[t0 + g*8];
        *(bf16x8*)&A1l[g*8] = *(const bf16x8*)&Uinl[t0 + g*8];
    }
    // col panel: row i of tile (b,j), re-swizzled per destination row j
    int isw = i & 7;
    #pragma unroll
    for (int it = 0; it < 4; ++it) {
        int g = tid + it*256, j = g>>4, ks = g&15;
        size_t src = (size_t)(b*NN + j)*TILE + i*128 + ((ks ^ isw) * 8);
        int dst = j*128 + ((ks ^ (j & 7)) * 8);
        *(bf16x8*)&A2h[dst] = *(const bf16x8*)&Uinh[src];
        *(bf16x8*)&A2l[dst] = *(const bf16x8*)&Uinl[src];
    }
    __syncthreads();
    int w = tid>>6, l = tid&63, lr = l&15, lk = l>>4;
    const int cb = (w*32 + lr)*NC + lk*8;
    f32x4 acc[4][2];
    #pragma unroll
    for (int mt = 0; mt < 4; ++mt) { acc[mt][0] = (f32x4)0.f; acc[mt][1] = (f32x4)0.f; }
    // eq MFMA: U@W0 + U^T@W1 (bf16x3 each)
    #pragma unroll
    for (int kt = 0; kt < 4; ++kt) {
        bf16x8 b0h0 = *(const bf16x8*)&W0h[cb + kt*32];
        bf16x8 b0l0 = *(const bf16x8*)&W0l[cb + kt*32];
        bf16x8 b1h0 = *(const bf16x8*)&W1h[cb + kt*32];
        bf16x8 b1l0 = *(const bf16x8*)&W1l[cb + kt*32];
        bf16x8 b0h1 = *(const bf16x8*)&W0h[cb + 16*NC + kt*32];
        bf16x8 b0l1 = *(const bf16x8*)&W0l[cb + 16*NC + kt*32];
        bf16x8 b1h1 = *(const bf16x8*)&W1h[cb + 16*NC + kt*32];
        bf16x8 b1l1 = *(const bf16x8*)&W1l[cb + 16*NC + kt*32];
        #pragma unroll
        for (int mt = 0; mt < 4; ++mt) {
            int row = mt*16 + lr;
            int slot = ((kt*4 + lk) ^ (row & 7)) * 8;
            bf16x8 a1h = *(const bf16x8*)&A1h[row*128 + slot];
            bf16x8 a1l = *(const bf16x8*)&A1l[row*128 + slot];
            bf16x8 a2h = *(const bf16x8*)&A2h[row*128 + slot];
            bf16x8 a2l = *(const bf16x8*)&A2l[row*128 + slot];
            MFMA(a1h, b0h0, acc[mt][0]); MFMA(a1h, b0l0, acc[mt][0]); MFMA(a1l, b0h0, acc[mt][0]);
            MFMA(a2h, b1h0, acc[mt][0]); MFMA(a2h, b1l0, acc[mt][0]); MFMA(a2l, b1h0, acc[mt][0]);
            MFMA(a1h, b0h1, acc[mt][1]); MFMA(a1h, b0l1, acc[mt][1]); MFMA(a1l, b0h1, acc[mt][1]);
            MFMA(a2h, b1h1, acc[mt][1]); MFMA(a2h, b1l1, acc[mt][1]); MFMA(a2l, b1h1, acc[mt][1]);
        }
    }
    __syncthreads();   // panels dead; stage eq acc
    #pragma unroll
    for (int mt = 0; mt < 4; ++mt)
        #pragma unroll
        for (int nt = 0; nt < 2; ++nt)
            #pragma unroll
            for (int q = 0; q < 4; ++q)
                Ls[(mt*16 + lk*4 + q)*128 + w*32 + nt*16 + lr] = acc[mt][nt][q];
    __syncthreads();
    // broadcasts + activation -> E tile (bf16 hi/lo)
    float mi = mask1[b*NN + i];
    #pragma unroll
    for (int it = 0; it < 4; ++it) {
        int g = tid + it*256, j = g>>4, ks = g&15, c0 = ks*8;
        float m2 = mi * mask1[b*NN + j];
        const float* Ai = A  + (size_t)(b*NN+i)*NC + c0;
        const float* Bj = Bc + (size_t)(b*NN+j)*NC + c0;
        const float* Gb = G  + (size_t)b*NC + c0;
        bf16x8 hv, lv;
        #pragma unroll
        for (int q = 0; q < 8; ++q) {
            float v = Ls[j*128 + c0 + q] + Ai[q] + Bj[q] + Gb[q];
            if (j == i) v += Dgv[(size_t)(b*NN+i)*NC + c0 + q] + Gd[(size_t)b*NC + c0 + q];
            v = lrelu(v) * m2;
            unsigned short hh = f2bf(v);
            hv[q] = (short)hh;
            lv[q] = (short)f2bf(v - bf2f(hh));
        }
        int slot = (ks ^ (j & 7)) * 8;
        *(bf16x8*)&Eh[j*128 + slot] = hv;
        *(bf16x8*)&El[j*128 + slot] = lv;
    }
    __syncthreads();
    // msg MFMA
    #pragma unroll
    for (int mt = 0; mt < 4; ++mt) { acc[mt][0] = (f32x4)0.f; acc[mt][1] = (f32x4)0.f; }
    #pragma unroll
    for (int kt = 0; kt < 4; ++kt) {
        bf16x8 bh0 = *(const bf16x8*)&Wmh[cb + kt*32];
        bf16x8 bl0 = *(const bf16x8*)&Wml[cb + kt*32];
        bf16x8 bh1 = *(const bf16x8*)&Wmh[cb + 16*NC + kt*32];
        bf16x8 bl1 = *(const bf16x8*)&Wml[cb + 16*NC + kt*32];
        #pragma unroll
        for (int mt = 0; mt < 4; ++mt) {
            int row = mt*16 + lr;
            int slot = ((kt*4 + lk) ^ (row & 7)) * 8;
            bf16x8 ah = *(const bf16x8*)&Eh[row*128 + slot];
            bf16x8 al = *(const bf16x8*)&El[row*128 + slot];
            MFMA(ah, bh0, acc[mt][0]); MFMA(ah, bl0, acc[mt][0]); MFMA(al, bh0, acc[mt][0]);
            MFMA(ah, bh1, acc[mt][1]); MFMA(ah, bl1, acc[mt][1]); MFMA(al, bh1, acc[mt][1]);
        }
    }
    // stage msg acc (Ls region last read before msg MFMA's preceding barrier)
    #pragma unroll
    for (int mt = 0; mt < 4; ++mt)
        #pragma unroll
        for (int nt = 0; nt < 2; ++nt)
            #pragma unroll
            for (int q = 0; q < 4; ++q)
                Ls[(mt*16 + lk*4 + q)*128 + w*32 + nt*16 + lr] = acc[mt][nt][q];
    __syncthreads();
    // final epilogue
    float pr[8] = {0,0,0,0,0,0,0,0};
    #pragma unroll
    for (int it = 0; it < 4; ++it) {
        int g = tid + it*256, j = g>>4, ks = g&15, c0 = ks*8;
        float m2 = mi * mask1[b*NN + j];
        bf16x8 hv, lv;
        #pragma unroll
        for (int q = 0; q < 8; ++q) {
            float v = lrelu(Ls[j*128 + c0 + q] + mbias[c0+q]) * m2;
            pr[q] += v;
            if (j == i) diag[(size_t)(b*NN+i)*NC + c0 + q] = v;
            unsigned short hh = f2bf(v);
            hv[q] = (short)hh;
            lv[q] = (short)f2bf(v - bf2f(hh));
        }
        if (WOUT) {
            int slot = (ks ^ (j & 7)) * 8;
            *(bf16x8*)&Uoh[t0 + j*128 + slot] = hv;
            *(bf16x8*)&Uol[t0 + j*128 + slot] = lv;
        }
    }
    #pragma unroll
    for (int q = 0; q < 8; ++q) Ls2[(tid>>4)*128 + (tid&15)*8 + q] = pr[q];
    __syncthreads();
    if (tid < 128) {
        float s = 0.f;
        #pragma unroll
        for (int gb = 0; gb < 16; ++gb) s += Ls2[gb*128 + tid];
        rsum[(size_t)(b*NN+i)*NC + tid] = s / AVGF;
    }
}

// ---------------- csum (col sums over i) + folded red2 (G/Gd) ----------------
__global__ __launch_bounds__(256) void k_csum(
    const short* __restrict__ Uh, const short* __restrict__ Ul,
    const float* __restrict__ rsum, const float* __restrict__ diag,
    const float* __restrict__ Weq, const float* __restrict__ eqb,
    const float* __restrict__ eqbd,
    float* __restrict__ csum, float* __restrict__ G, float* __restrict__ Gd)
{
    __shared__ float ts[NC], trs[NC];
    int wg = blockIdx.x;                 // 128 blocks, xcd = b>>2
    int b = (wg & 7) * 4 + ((wg >> 3) & 3);
    int quarter = wg >> 5;
    int tid = threadIdx.x;
    int j = tid >> 2, ks = quarter * 4 + (tid & 3);
    int slot = (ks ^ (j & 7)) * 8;
    float acc[8] = {0,0,0,0,0,0,0,0};
    for (int i2 = 0; i2 < NN; ++i2) {
        size_t src = (size_t)(b*NN + i2)*TILE + j*128 + slot;
        bf16x8 h = *(const bf16x8*)&Uh[src];
        bf16x8 l2 = *(const bf16x8*)&Ul[src];
        #pragma unroll
        for (int q = 0; q < 8; ++q) acc[q] += bf2f((unsigned short)h[q]) + bf2f((unsigned short)l2[q]);
    }
    #pragma unroll
    for (int q = 0; q < 8; ++q) csum[(size_t)(b*NN + j)*NC + ks*8 + q] = acc[q] / AVGF;
    if (quarter == 0) {
        if (tid < 128) {
            float tt = 0.f, rr = 0.f;
            for (int i2 = 0; i2 < NN; ++i2) {
                tt += rsum[(size_t)(b*NN + i2)*NC + tid];
                rr += diag[(size_t)(b*NN + i2)*NC + tid];
            }
            ts[tid] = tt / AVGF;
            trs[tid] = rr / AVGF;
        }
        __syncthreads();
        if (tid < 128) {
            float g = eqb[tid], gd = eqbd[tid];
            for (int k = 0; k < NC; ++k) {
                float tv = ts[k], rv = trs[k];
                g  += tv * Weq[(11*NC + k)*NC + tid] + rv * Weq[(13*NC + k)*NC + tid];
                gd += tv * Weq[(12*NC + k)*NC + tid] + rv * Weq[(14*NC + k)*NC + tid];
            }
            G[b*NC + tid] = g;
            Gd[b*NC + tid] = gd;
        }
    }
}

// ---------------- per-row broadcast vectors A (i), Bc (j), Dg (diag) ----------------
__global__ __launch_bounds__(256) void k_red3(
    const float* __restrict__ rsum, const float* __restrict__ csum,
    const float* __restrict__ diag, const float* __restrict__ Weq,
    float* __restrict__ A, float* __restrict__ Bc, float* __restrict__ Dgv)
{
    int blk = blockIdx.x;
    int row0 = blk * 8;
    int tid = threadIdx.x;
    int c = tid & 127, half = tid >> 7;
    __shared__ float ds[8][NC], rs[8][NC], cs[8][NC];
    for (int idx = tid; idx < 8 * NC; idx += 256) {
        int r = idx >> 7, cc = idx & 127;
        ds[r][cc] = diag[(size_t)(row0 + r) * NC + cc];
        rs[r][cc] = rsum[(size_t)(row0 + r) * NC + cc];
        cs[r][cc] = csum[(size_t)(row0 + r) * NC + cc];
    }
    __syncthreads();
    float aA[4] = {0,0,0,0}, aB[4] = {0,0,0,0}, aD[4] = {0,0,0,0};
    for (int k = 0; k < NC; ++k) {
        float w2  = Weq[(2  * NC + k) * NC + c];
        float w3  = Weq[(3  * NC + k) * NC + c];
        float w4  = Weq[(4  * NC + k) * NC + c];
        float w5  = Weq[(5  * NC + k) * NC + c];
        float w6  = Weq[(6  * NC + k) * NC + c];
        float w7  = Weq[(7  * NC + k) * NC + c];
        float w8  = Weq[(8  * NC + k) * NC + c];
        float w9  = Weq[(9  * NC + k) * NC + c];
        float w10 = Weq[(10 * NC + k) * NC + c];
        #pragma unroll
        for (int r = 0; r < 4; ++r) {
            int rr = half * 4 + r;
            float dv = ds[rr][k], rv = rs[rr][k], cv = cs[rr][k];
            aA[r] += dv * w3 + rv * w5 + cv * w7;
            aB[r] += dv * w4 + rv * w6 + cv * w8;
            aD[r] += dv * w2 + rv * w9 + cv * w10;
        }
    }
    #pragma unroll
    for (int r = 0; r < 4; ++r) {
        size_t o = (size_t)(row0 + half * 4 + r) * NC + c;
        A[o] = aA[r];
        Bc[o] = aB[r];
        Dgv[o] = aD[r];
    }
}

// ---------------- Eq2to0 head + output MLP ----------------
__global__ __launch_bounds__(128) void k_final(
    const float* __restrict__ rsum, const float* __restrict__ diag,
    const float* __restrict__ w20, const float* __restrict__ b20,
    const float* __restrict__ wmlp, const float* __restrict__ bmlp,
    float* __restrict__ outp)
{
    int b = blockIdx.x;
    int c = threadIdx.x;
    __shared__ float agg0[NC], agg1[NC], act3[NC];
    float dgv = 0.f, tot = 0.f;
    for (int i = 0; i < NN; ++i) {
        dgv += diag[(size_t)(b * NN + i) * NC + c];
        tot += rsum[(size_t)(b * NN + i) * NC + c];
    }
    agg0[c] = lrelu(dgv / AVGF);
    agg1[c] = lrelu(tot / AVGF);
    __syncthreads();
    float a3 = b20[c];
    for (int k = 0; k < NC; ++k)
        a3 += agg0[k] * w20[k * NC + c] + agg1[k] * w20[(NC + k) * NC + c];
    act3[c] = a3;
    __syncthreads();
    if (c < 2) {
        float o = bmlp[c];
        for (int d = 0; d < NC; ++d) o += act3[d] * wmlp[d * 2 + c];
        outp[b * 2 + c] = o;
    }
}

extern "C" void kernel_launch(void* const* d_in, const int* in_sizes, int n_in,
                              void* d_out, int out_size, void* d_ws, size_t ws_size,
                              hipStream_t stream)
{
    const float* momenta = (const float*)d_in[0];
    const float* scalars = (const float*)d_in[1];
    const int*   nobj    = (const int*)d_in[2];
    const float* w_lin   = (const float*)d_in[3];
    const float* alpha   = (const float*)d_in[4];
    const float* w_in    = (const float*)d_in[5];
    const float* b_in    = (const float*)d_in[6];
    const float *msgW[4], *msgB[4], *eqW[4], *eqB[4], *eqBd[4];
    const float *wm0, *bm0, *w20, *b20, *wmlp, *bmlp;
    if (n_in >= 33) {
        for (int l = 0; l < 4; ++l) {
            msgW[l] = (const float*)d_in[7 + l];
            msgB[l] = (const float*)d_in[11 + l];
            eqW[l]  = (const float*)d_in[15 + l];
            eqB[l]  = (const float*)d_in[19 + l];
            eqBd[l] = (const float*)d_in[23 + l];
        }
        wm0  = (const float*)d_in[27]; bm0  = (const float*)d_in[28];
        w20  = (const float*)d_in[29]; b20  = (const float*)d_in[30];
        wmlp = (const float*)d_in[31]; bmlp = (const float*)d_in[32];
    } else {
        for (int l = 0; l < 4; ++l) {
            msgW[l] = (const float*)d_in[7] + (size_t)l * NC * NC;
            msgB[l] = (const float*)d_in[8] + l * NC;
            eqW[l]  = (const float*)d_in[9] + (size_t)l * 15 * NC * NC;
            eqB[l]  = (const float*)d_in[10] + l * NC;
            eqBd[l] = (const float*)d_in[11] + l * NC;
        }
        wm0  = (const float*)d_in[12]; bm0  = (const float*)d_in[13];
        w20  = (const float*)d_in[14]; b20  = (const float*)d_in[15];
        wmlp = (const float*)d_in[16]; bmlp = (const float*)d_in[17];
    }

    // ---- workspace layout: bf16 tile buffers first, then weights, then fp32 ----
    const size_t TN2 = (size_t)NB * NN * TILE;       // shorts per tile array
    short* Xh = (short*)d_ws;
    short* Xl = Xh + TN2;
    short* Yh = Xl + TN2;
    short* Yl = Yh + TN2;
    short* SW = Yl + TN2;                            // 13 * 32768 shorts
    float* fp = (float*)(((uintptr_t)(SW + 13 * 32768) + 15) & ~(uintptr_t)15);
    const size_t RN = (size_t)NB * NN * NC;
    float* rsum = fp;
    float* csum = rsum + RN;
    float* diag = csum + RN;
    float* Aa   = diag + RN;
    float* Bb   = Aa + RN;
    float* Dgv  = Bb + RN;
    float* G    = Dgv + RN;
    float* Gd   = G + NB * NC;
    float* mask1 = Gd + NB * NC;
    float* P0   = mask1 + NB * NN;
    float* P1   = P0 + (size_t)NB * NN * NCS;
    float* P2   = P1 + (size_t)NB * NN * NCS;
    float* Ps3  = P2 + (size_t)NB * NN * NCS;
    float* Ps4  = Ps3 + NB * NCS;
    size_t need = (size_t)((char*)(Ps4 + NB * NCS) - (char*)d_ws);
    if (ws_size < need) return;

    k_split<<<dim3(64, 13), 256, 0, stream>>>(msgW[0], msgW[1], msgW[2], msgW[3],
                                              wm0, eqW[0], eqW[1], eqW[2], eqW[3], SW);
    k_prep<<<NB, 256, 0, stream>>>(scalars, nobj, w_in, mask1, P0, P1, P2, Ps3, Ps4);

    short* Wm0h = SW;                                 // msgW[0]
    k_f0<<<NB * NN, 256, 0, stream>>>(momenta, mask1, P0, P1, P2, Ps3, Ps4,
                                      b_in, w_lin, alpha, Wm0h, Wm0h + 16384,
                                      msgB[0], Xh, Xl, rsum, diag);

    short *inh = Xh, *inl = Xl, *outh = Yh, *outl = Yl;
    for (int l = 0; l < 4; ++l) {
        k_csum<<<128, 256, 0, stream>>>(inh, inl, rsum, diag, eqW[l], eqB[l], eqBd[l],
                                        csum, G, Gd);
        k_red3<<<NB * NN / 8, 256, 0, stream>>>(rsum, csum, diag, eqW[l], Aa, Bb, Dgv);
        short* W0 = SW + (size_t)(5 + 2 * l) * 32768;
        short* W1 = SW + (size_t)(6 + 2 * l) * 32768;
        if (l < 3) {
            short* Wm = SW + (size_t)(l + 1) * 32768;
            k_feq<1><<<NB * NN, 256, 0, stream>>>(inh, inl, W0, W0 + 16384,
                                                  W1, W1 + 16384, Wm, Wm + 16384,
                                                  msgB[l + 1], Aa, Bb, Dgv, G, Gd, mask1,
                                                  outh, outl, rsum, diag);
            short* th = inh; inh = outh; outh = th;
            short* tl = inl; inl = outl; outl = tl;
        } else {
            short* Wm = SW + (size_t)4 * 32768;       // wm0
            k_feq<0><<<NB * NN, 256, 0, stream>>>(inh, inl, W0, W0 + 16384,
                                                  W1, W1 + 16384, Wm, Wm + 16384,
                                                  bm0, Aa, Bb, Dgv, G, Gd, mask1,
                                                  outh, outl, rsum, diag);
        }
    }
    k_final<<<NB, 128, 0, stream>>>(rsum, diag, w20, b20, wmlp, bmlp, (float*)d_out);
}

// Round 4
// 779.938 us; speedup vs baseline: 2.1019x; 1.1945x over previous
//
#include <hip/hip_runtime.h>
#include <math.h>

#define NB 32
#define NN 64
#define NS 9
#define NCS 32
#define NC 128
#define AVGF 49.0f
#define TILE 8192   // shorts per (b,i) tile: 64 rows x 128 ch

typedef __attribute__((ext_vector_type(8))) short bf16x8;
typedef __attribute__((ext_vector_type(4))) float f32x4;

#define MFMA(a,bb,c) c = __builtin_amdgcn_mfma_f32_16x16x32_bf16(a,bb,c,0,0,0)

__device__ __forceinline__ float lrelu(float x){ return x>0.f ? x : 0.01f*x; }
__device__ __forceinline__ unsigned short f2bf(float x){
    unsigned u=__float_as_uint(x);
    return (unsigned short)((u + 0x7FFF + ((u>>16)&1)) >> 16);
}
__device__ __forceinline__ float bf2f(unsigned short h){ return __uint_as_float(((unsigned)h)<<16); }
// XCD-affinity map: batch pinned to xcd = wgid%8 (4 batches/XCD, 64 blocks contiguous)
__device__ __forceinline__ void map_bi(int wg,int&b,int&i){ int x=wg&7,q=wg>>3; b=x*4+(q>>6); i=q&63; }
// conflict-free f32 staging swizzle (write side: exactly 2 lanes/bank)
__device__ __forceinline__ int sa(int row,int col){ return row*128 + (col ^ ((row&7)<<2)); }

// ---------------- split weights: W[k][c] fp32 -> [c][k] bf16 hi/lo ----------------
__global__ __launch_bounds__(256) void k_split(
    const float* __restrict__ m0, const float* __restrict__ m1,
    const float* __restrict__ m2, const float* __restrict__ m3,
    const float* __restrict__ m4, const float* __restrict__ e0,
    const float* __restrict__ e1, const float* __restrict__ e2,
    const float* __restrict__ e3, short* __restrict__ outbuf)
{
    int m = blockIdx.y;
    const float* src;
    if (m < 5) src = (m == 0 ? m0 : m == 1 ? m1 : m == 2 ? m2 : m == 3 ? m3 : m4);
    else {
        int l = (m - 5) >> 1, sub = (m - 5) & 1;
        const float* e = (l == 0 ? e0 : l == 1 ? e1 : l == 2 ? e2 : e3);
        src = e + sub * NC * NC;
    }
    int idx = blockIdx.x * 256 + threadIdx.x;
    int k = idx >> 7, c = idx & 127;
    float x = src[idx];
    unsigned short hh = f2bf(x);
    unsigned short ll = f2bf(x - bf2f(hh));
    short* oh = outbuf + (size_t)m * 32768;
    oh[c * NC + k] = (short)hh;
    oh[16384 + c * NC + k] = (short)ll;
}

// ---------------- prep: mask1, eq1to2 projections ----------------
__global__ __launch_bounds__(256) void k_prep(
    const float* __restrict__ scalars, const int* __restrict__ nobj,
    const float* __restrict__ w_in,
    float* __restrict__ mask1, float* __restrict__ P0,
    float* __restrict__ P1, float* __restrict__ P2,
    float* __restrict__ Ps3, float* __restrict__ Ps4)
{
    int b = blockIdx.x, tid = threadIdx.x;
    __shared__ float xs[NN][NS];
    __shared__ float ss[NS];
    int cnt = nobj[b];
    for (int idx = tid; idx < NN * NS; idx += 256) {
        int i = idx / NS, s = idx - i * NS;
        xs[i][s] = (i < cnt) ? scalars[(b * NN + i) * NS + s] : 0.0f;
    }
    if (tid < NN) mask1[b * NN + tid] = (tid < cnt) ? 1.0f : 0.0f;
    __syncthreads();
    if (tid < NS) {
        float a = 0.f;
        for (int i = 0; i < NN; ++i) a += xs[i][tid];
        ss[tid] = a / AVGF;
    }
    __syncthreads();
    for (int idx = tid; idx < NN * NCS; idx += 256) {
        int i = idx >> 5, d = idx & 31;
        float a0 = 0.f, a1 = 0.f, a2 = 0.f;
        #pragma unroll
        for (int s = 0; s < NS; ++s) {
            float x = xs[i][s];
            a0 += x * w_in[(0 * NS + s) * NCS + d];
            a1 += x * w_in[(1 * NS + s) * NCS + d];
            a2 += x * w_in[(2 * NS + s) * NCS + d];
        }
        P0[(b * NN + i) * NCS + d] = a0;
        P1[(b * NN + i) * NCS + d] = a1;
        P2[(b * NN + i) * NCS + d] = a2;
    }
    if (tid < NCS) {
        float a3 = 0.f, a4 = 0.f;
        #pragma unroll
        for (int s = 0; s < NS; ++s) {
            a3 += ss[s] * w_in[(3 * NS + s) * NCS + tid];
            a4 += ss[s] * w_in[(4 * NS + s) * NCS + tid];
        }
        Ps3[b * NCS + tid] = a3;
        Ps4[b * NCS + tid] = a4;
    }
}

// ---------------- F0: build T0 tile in LDS, msg1 MFMA, write U1 tiles + rsum/diag ----------------
__global__ __launch_bounds__(512, 4) void k_f0(
    const float* __restrict__ momenta, const float* __restrict__ mask1,
    const float* __restrict__ P0, const float* __restrict__ P1,
    const float* __restrict__ P2, const float* __restrict__ Ps3,
    const float* __restrict__ Ps4, const float* __restrict__ b_in,
    const float* __restrict__ w_lin, const float* __restrict__ alpha,
    const short* __restrict__ Wh, const short* __restrict__ Wl,
    const float* __restrict__ bias,
    short* __restrict__ Uh, short* __restrict__ Ul,
    float* __restrict__ rsum, float* __restrict__ diag)
{
    __shared__ __align__(16) char smem[49664];
    short* Eh = (short*)smem;                 // [0,16K)
    short* El = Eh + TILE;                    // [16K,32K)
    float* Ls = (float*)smem;                 // overlay [0,32K) after msg MFMA
    float* dots = (float*)(smem + 32768);     // 64
    float* mjv  = dots + 64;                  // 64
    float* Ls2  = mjv + 64;                   // [32][128] 16KB
    int tid = threadIdx.x;
    int b, i; map_bi(blockIdx.x, b, i);
    const int rb = b * NN;
    if (tid < NN) {
        const float* pi = momenta + (size_t)(rb + i) * 4;
        const float* pj = momenta + (size_t)(rb + tid) * 4;
        dots[tid] = pi[0]*pj[0] - pi[1]*pj[1] - pi[2]*pj[2] - pi[3]*pj[3];
        mjv[tid] = mask1[rb + tid];
    }
    __syncthreads();
    float mi = mask1[rb + i];
    int pj = tid >> 4, pks = tid & 15, pc0 = pks * 8;
    // build T0 tile -> Eh/El
    #pragma unroll
    for (int it = 0; it < 2; ++it) {
        int j = pj + it * 32;
        float m2 = mi * mjv[j];
        float v[8];
        if (pks < 4) {
            #pragma unroll
            for (int q = 0; q < 8; ++q) {
                float x = P0[(size_t)(rb+i)*NCS + pc0+q] + P1[(size_t)(rb+j)*NCS + pc0+q]
                        + Ps3[b*NCS + pc0+q] + b_in[pc0+q];
                if (j == i) x += P2[(size_t)(rb+i)*NCS + pc0+q] + Ps4[b*NCS + pc0+q];
                v[q] = lrelu(x) * m2;
            }
        } else {
            int c2 = pc0 - NCS;
            float dj = dots[j];
            #pragma unroll
            for (int q = 0; q < 8; ++q) {
                float r = dj * w_lin[c2+q];
                v[q] = alpha[c2+q] * copysignf(log1pf(fabsf(r)), r) * m2;
            }
        }
        bf16x8 hv, lv;
        #pragma unroll
        for (int q = 0; q < 8; ++q) {
            unsigned short hh = f2bf(v[q]);
            hv[q] = (short)hh;
            lv[q] = (short)f2bf(v[q] - bf2f(hh));
        }
        int slot = (pks ^ (j & 7)) * 8;
        *(bf16x8*)&Eh[j*128 + slot] = hv;
        *(bf16x8*)&El[j*128 + slot] = lv;
    }
    __syncthreads();
    // msg MFMA (8 waves: 2M x 4N)
    int w = tid >> 6, l = tid & 63, lr = l & 15, lk = l >> 4;
    int wr = w >> 2, wc = w & 3;
    const int cb = (wc*32 + lr)*NC + lk*8;
    f32x4 acc[2][2];
    acc[0][0]=(f32x4)0.f; acc[0][1]=(f32x4)0.f; acc[1][0]=(f32x4)0.f; acc[1][1]=(f32x4)0.f;
    #pragma unroll
    for (int kt = 0; kt < 4; ++kt) {
        #pragma unroll
        for (int nt = 0; nt < 2; ++nt) {
            bf16x8 bh = *(const bf16x8*)&Wh[cb + nt*16*NC + kt*32];
            bf16x8 bl = *(const bf16x8*)&Wl[cb + nt*16*NC + kt*32];
            #pragma unroll
            for (int mt = 0; mt < 2; ++mt) {
                int row = (wr*2 + mt)*16 + lr;
                int slot = ((kt*4 + lk) ^ (row & 7)) * 8;
                bf16x8 ah = *(const bf16x8*)&Eh[row*128 + slot];
                bf16x8 al = *(const bf16x8*)&El[row*128 + slot];
                MFMA(ah, bh, acc[mt][nt]); MFMA(ah, bl, acc[mt][nt]); MFMA(al, bh, acc[mt][nt]);
            }
        }
    }
    __syncthreads();
    #pragma unroll
    for (int mt = 0; mt < 2; ++mt)
        #pragma unroll
        for (int nt = 0; nt < 2; ++nt)
            #pragma unroll
            for (int q = 0; q < 4; ++q) {
                int row = (wr*2 + mt)*16 + lk*4 + q;
                int col = wc*32 + nt*16 + lr;
                Ls[sa(row, col)] = acc[mt][nt][q];
            }
    __syncthreads();
    // epilogue
    size_t t0 = (size_t)(rb + i) * TILE;
    float pr[8] = {0,0,0,0,0,0,0,0};
    #pragma unroll
    for (int it = 0; it < 2; ++it) {
        int j = pj + it*32;
        float m2 = mi * mjv[j];
        const float* p = Ls + j*128 + (pc0 ^ ((j & 6) << 2));
        float4 qa = *(const float4*)(p + ((j & 1) << 2));
        float4 qb = *(const float4*)(p + (4 ^ ((j & 1) << 2)));
        float vv[8] = {qa.x,qa.y,qa.z,qa.w, qb.x,qb.y,qb.z,qb.w};
        bf16x8 hv, lv;
        #pragma unroll
        for (int q = 0; q < 8; ++q) {
            float v = lrelu(vv[q] + bias[pc0+q]) * m2;
            pr[q] += v;
            if (j == i) diag[(size_t)(rb+i)*NC + pc0 + q] = v;
            unsigned short hh = f2bf(v);
            hv[q] = (short)hh;
            lv[q] = (short)f2bf(v - bf2f(hh));
        }
        int slot = (pks ^ (j & 7)) * 8;
        *(bf16x8*)&Uh[t0 + j*128 + slot] = hv;
        *(bf16x8*)&Ul[t0 + j*128 + slot] = lv;
    }
    #pragma unroll
    for (int q = 0; q < 8; ++q) Ls2[pj*128 + pc0 + q] = pr[q];
    __syncthreads();
    if (tid < 128) {
        float s = 0.f;
        #pragma unroll
        for (int g2 = 0; g2 < 32; ++g2) s += Ls2[g2*128 + tid];
        rsum[(size_t)(rb+i)*NC + tid] = s / AVGF;
    }
}

// ---------------- F_eq: eq_l (U@W0 + U^T@W1 + broadcasts) fused with msg_{l+1} ----------------
template<int WOUT>
__global__ __launch_bounds__(512, 4) void k_feq(
    const short* __restrict__ Uinh, const short* __restrict__ Uinl,
    const short* __restrict__ W0h, const short* __restrict__ W0l,
    const short* __restrict__ W1h, const short* __restrict__ W1l,
    const short* __restrict__ Wmh, const short* __restrict__ Wml,
    const float* __restrict__ mbias,
    const float* __restrict__ A, const float* __restrict__ Bc,
    const float* __restrict__ Dgv, const float* __restrict__ G,
    const float* __restrict__ Gd, const float* __restrict__ mask1,
    short* __restrict__ Uoh, short* __restrict__ Uol,
    float* __restrict__ rsum, float* __restrict__ diag)
{
    __shared__ __align__(16) char smem[65536];
    short* A1h = (short*)smem;          // [0,16K)
    short* A1l = A1h + TILE;            // [16K,32K)
    short* A2h = A1l + TILE;            // [32K,48K)
    short* A2l = A2h + TILE;            // [48K,64K)
    float* Ls  = (float*)smem;          // overlay [0,32K) after eq MFMA
    short* Eh  = A2h;                   // overlay [32K,48K)
    short* El  = A2l;                   // overlay [48K,64K)
    float* Ls2 = (float*)(smem + 32768);// overlay [32K,48K) after msg MFMA
    int tid = threadIdx.x;
    int b, i; map_bi(blockIdx.x, b, i);
    const int rb = b * NN;
    size_t t0 = (size_t)(rb + i) * TILE;
    int pj = tid >> 4, pks = tid & 15, pc0 = pks * 8;

    // prefetch row-invariant broadcast vectors into registers
    float Aif[8], Gbf[8], mbf[8];
    {
        float4 a0 = *(const float4*)(A + (size_t)(rb+i)*NC + pc0);
        float4 a1 = *(const float4*)(A + (size_t)(rb+i)*NC + pc0 + 4);
        Aif[0]=a0.x; Aif[1]=a0.y; Aif[2]=a0.z; Aif[3]=a0.w;
        Aif[4]=a1.x; Aif[5]=a1.y; Aif[6]=a1.z; Aif[7]=a1.w;
        float4 g0 = *(const float4*)(G + (size_t)b*NC + pc0);
        float4 g1 = *(const float4*)(G + (size_t)b*NC + pc0 + 4);
        Gbf[0]=g0.x; Gbf[1]=g0.y; Gbf[2]=g0.z; Gbf[3]=g0.w;
        Gbf[4]=g1.x; Gbf[5]=g1.y; Gbf[6]=g1.z; Gbf[7]=g1.w;
        float4 m0 = *(const float4*)(mbias + pc0);
        float4 m1 = *(const float4*)(mbias + pc0 + 4);
        mbf[0]=m0.x; mbf[1]=m0.y; mbf[2]=m0.z; mbf[3]=m0.w;
        mbf[4]=m1.x; mbf[5]=m1.y; mbf[6]=m1.z; mbf[7]=m1.w;
    }
    float mi = mask1[rb + i], mj0 = mask1[rb + pj], mj1 = mask1[rb + pj + 32];

    // row panel: straight tile copy (already MFMA layout)
    #pragma unroll
    for (int it = 0; it < 2; ++it) {
        int g = tid + it * 512;
        *(bf16x8*)&A1h[g*8] = *(const bf16x8*)&Uinh[t0 + g*8];
        *(bf16x8*)&A1l[g*8] = *(const bf16x8*)&Uinl[t0 + g*8];
    }
    // col panel: row i of tile (b,j), re-swizzled per destination row j
    int isw = i & 7;
    #pragma unroll
    for (int it = 0; it < 2; ++it) {
        int g = tid + it * 512, j = g >> 4, ks = g & 15;
        size_t src = (size_t)(rb + j)*TILE + i*128 + ((ks ^ isw) * 8);
        int dst = j*128 + ((ks ^ (j & 7)) * 8);
        *(bf16x8*)&A2h[dst] = *(const bf16x8*)&Uinh[src];
        *(bf16x8*)&A2l[dst] = *(const bf16x8*)&Uinl[src];
    }
    __syncthreads();
    int w = tid >> 6, l = tid & 63, lr = l & 15, lk = l >> 4;
    int wr = w >> 2, wc = w & 3;
    const int cb = (wc*32 + lr)*NC + lk*8;
    f32x4 acc[2][2];
    acc[0][0]=(f32x4)0.f; acc[0][1]=(f32x4)0.f; acc[1][0]=(f32x4)0.f; acc[1][1]=(f32x4)0.f;
    // eq MFMA: U@W0 + U^T@W1 (bf16x3 each)
    #pragma unroll
    for (int kt = 0; kt < 4; ++kt) {
        #pragma unroll
        for (int nt = 0; nt < 2; ++nt) {
            bf16x8 b0h = *(const bf16x8*)&W0h[cb + nt*16*NC + kt*32];
            bf16x8 b0l = *(const bf16x8*)&W0l[cb + nt*16*NC + kt*32];
            bf16x8 b1h = *(const bf16x8*)&W1h[cb + nt*16*NC + kt*32];
            bf16x8 b1l = *(const bf16x8*)&W1l[cb + nt*16*NC + kt*32];
            #pragma unroll
            for (int mt = 0; mt < 2; ++mt) {
                int row = (wr*2 + mt)*16 + lr;
                int slot = ((kt*4 + lk) ^ (row & 7)) * 8;
                bf16x8 a1h = *(const bf16x8*)&A1h[row*128 + slot];
                bf16x8 a1l = *(const bf16x8*)&A1l[row*128 + slot];
                bf16x8 a2h = *(const bf16x8*)&A2h[row*128 + slot];
                bf16x8 a2l = *(const bf16x8*)&A2l[row*128 + slot];
                MFMA(a1h,b0h,acc[mt][nt]); MFMA(a1h,b0l,acc[mt][nt]); MFMA(a1l,b0h,acc[mt][nt]);
                MFMA(a2h,b1h,acc[mt][nt]); MFMA(a2h,b1l,acc[mt][nt]); MFMA(a2l,b1h,acc[mt][nt]);
            }
        }
    }
    __syncthreads();   // panels dead
    #pragma unroll
    for (int mt = 0; mt < 2; ++mt)
        #pragma unroll
        for (int nt = 0; nt < 2; ++nt)
            #pragma unroll
            for (int q = 0; q < 4; ++q) {
                int row = (wr*2 + mt)*16 + lk*4 + q;
                int col = wc*32 + nt*16 + lr;
                Ls[sa(row, col)] = acc[mt][nt][q];
            }
    __syncthreads();
    // broadcasts + activation -> E tile (bf16 hi/lo)
    #pragma unroll
    for (int it = 0; it < 2; ++it) {
        int j = pj + it*32;
        float m2 = mi * (it ? mj1 : mj0);
        float Bf[8];
        {
            float4 b0 = *(const float4*)(Bc + (size_t)(rb+j)*NC + pc0);
            float4 b1 = *(const float4*)(Bc + (size_t)(rb+j)*NC + pc0 + 4);
            Bf[0]=b0.x; Bf[1]=b0.y; Bf[2]=b0.z; Bf[3]=b0.w;
            Bf[4]=b1.x; Bf[5]=b1.y; Bf[6]=b1.z; Bf[7]=b1.w;
        }
        const float* p = Ls + j*128 + (pc0 ^ ((j & 6) << 2));
        float4 qa = *(const float4*)(p + ((j & 1) << 2));
        float4 qb = *(const float4*)(p + (4 ^ ((j & 1) << 2)));
        float vv[8] = {qa.x,qa.y,qa.z,qa.w, qb.x,qb.y,qb.z,qb.w};
        bf16x8 hv, lv;
        #pragma unroll
        for (int q = 0; q < 8; ++q) {
            float v = vv[q] + Aif[q] + Bf[q] + Gbf[q];
            if (j == i) v += Dgv[(size_t)(rb+i)*NC + pc0 + q] + Gd[(size_t)b*NC + pc0 + q];
            v = lrelu(v) * m2;
            unsigned short hh = f2bf(v);
            hv[q] = (short)hh;
            lv[q] = (short)f2bf(v - bf2f(hh));
        }
        int slot = (pks ^ (j & 7)) * 8;
        *(bf16x8*)&Eh[j*128 + slot] = hv;
        *(bf16x8*)&El[j*128 + slot] = lv;
    }
    __syncthreads();
    // msg MFMA
    acc[0][0]=(f32x4)0.f; acc[0][1]=(f32x4)0.f; acc[1][0]=(f32x4)0.f; acc[1][1]=(f32x4)0.f;
    #pragma unroll
    for (int kt = 0; kt < 4; ++kt) {
        #pragma unroll
        for (int nt = 0; nt < 2; ++nt) {
            bf16x8 bh = *(const bf16x8*)&Wmh[cb + nt*16*NC + kt*32];
            bf16x8 bl = *(const bf16x8*)&Wml[cb + nt*16*NC + kt*32];
            #pragma unroll
            for (int mt = 0; mt < 2; ++mt) {
                int row = (wr*2 + mt)*16 + lr;
                int slot = ((kt*4 + lk) ^ (row & 7)) * 8;
                bf16x8 ah = *(const bf16x8*)&Eh[row*128 + slot];
                bf16x8 al = *(const bf16x8*)&El[row*128 + slot];
                MFMA(ah, bh, acc[mt][nt]); MFMA(ah, bl, acc[mt][nt]); MFMA(al, bh, acc[mt][nt]);
            }
        }
    }
    // stage msg acc into Ls [0,32K): disjoint from Eh/El reads, Ls last read pre-barrier
    #pragma unroll
    for (int mt = 0; mt < 2; ++mt)
        #pragma unroll
        for (int nt = 0; nt < 2; ++nt)
            #pragma unroll
            for (int q = 0; q < 4; ++q) {
                int row = (wr*2 + mt)*16 + lk*4 + q;
                int col = wc*32 + nt*16 + lr;
                Ls[sa(row, col)] = acc[mt][nt][q];
            }
    __syncthreads();
    // final epilogue
    float pr[8] = {0,0,0,0,0,0,0,0};
    #pragma unroll
    for (int it = 0; it < 2; ++it) {
        int j = pj + it*32;
        float m2 = mi * (it ? mj1 : mj0);
        const float* p = Ls + j*128 + (pc0 ^ ((j & 6) << 2));
        float4 qa = *(const float4*)(p + ((j & 1) << 2));
        float4 qb = *(const float4*)(p + (4 ^ ((j & 1) << 2)));
        float vv[8] = {qa.x,qa.y,qa.z,qa.w, qb.x,qb.y,qb.z,qb.w};
        bf16x8 hv, lv;
        #pragma unroll
        for (int q = 0; q < 8; ++q) {
            float v = lrelu(vv[q] + mbf[q]) * m2;
            pr[q] += v;
            if (j == i) diag[(size_t)(rb+i)*NC + pc0 + q] = v;
            unsigned short hh = f2bf(v);
            hv[q] = (short)hh;
            lv[q] = (short)f2bf(v - bf2f(hh));
        }
        if (WOUT) {
            int slot = (pks ^ (j & 7)) * 8;
            *(bf16x8*)&Uoh[t0 + j*128 + slot] = hv;
            *(bf16x8*)&Uol[t0 + j*128 + slot] = lv;
        }
    }
    #pragma unroll
    for (int q = 0; q < 8; ++q) Ls2[pj*128 + pc0 + q] = pr[q];
    __syncthreads();
    if (tid < 128) {
        float s = 0.f;
        #pragma unroll
        for (int g2 = 0; g2 < 32; ++g2) s += Ls2[g2*128 + tid];
        rsum[(size_t)(rb+i)*NC + tid] = s / AVGF;
    }
}

// ---------------- csum partials: 512 blocks = 32b x 4quarter x 4chunk ----------------
__global__ __launch_bounds__(256) void k_csum(
    const short* __restrict__ Uh, const short* __restrict__ Ul,
    float* __restrict__ pcsum)
{
    int wg = blockIdx.x;
    int b = (wg & 7) * 4 + ((wg >> 3) & 3);
    int rest = wg >> 5;                  // 0..15
    int quarter = rest & 3, chunk = rest >> 2;
    int tid = threadIdx.x;
    int j = tid >> 2, ks = quarter * 4 + (tid & 3);
    int slot = (ks ^ (j & 7)) * 8;
    float acc[8] = {0,0,0,0,0,0,0,0};
    for (int t = 0; t < 16; ++t) {
        int i2 = chunk * 16 + t;
        size_t src = (size_t)(b*NN + i2)*TILE + j*128 + slot;
        bf16x8 h = *(const bf16x8*)&Uh[src];
        bf16x8 l2 = *(const bf16x8*)&Ul[src];
        #pragma unroll
        for (int q = 0; q < 8; ++q)
            acc[q] += bf2f((unsigned short)h[q]) + bf2f((unsigned short)l2[q]);
    }
    #pragma unroll
    for (int q = 0; q < 8; ++q)
        pcsum[(size_t)chunk * NB*NN*NC + (size_t)(b*NN + j)*NC + ks*8 + q] = acc[q];
}

// ---------------- G/Gd (total-sum & trace basis terms) ----------------
__global__ __launch_bounds__(128) void k_gg(
    const float* __restrict__ rsum, const float* __restrict__ diag,
    const float* __restrict__ Weq, const float* __restrict__ eqb,
    const float* __restrict__ eqbd, float* __restrict__ G, float* __restrict__ Gd)
{
    int b = blockIdx.x;
    int c = threadIdx.x;
    __shared__ float ts[NC], trs[NC];
    float tt = 0.f, rr = 0.f;
    for (int i = 0; i < NN; ++i) {
        tt += rsum[(size_t)(b * NN + i) * NC + c];
        rr += diag[(size_t)(b * NN + i) * NC + c];
    }
    ts[c] = tt / AVGF;
    trs[c] = rr / AVGF;
    __syncthreads();
    float g = eqb[c], gd = eqbd[c];
    for (int k = 0; k < NC; ++k) {
        float tv = ts[k], rv = trs[k];
        g  += tv * Weq[(11 * NC + k) * NC + c] + rv * Weq[(13 * NC + k) * NC + c];
        gd += tv * Weq[(12 * NC + k) * NC + c] + rv * Weq[(14 * NC + k) * NC + c];
    }
    G[b * NC + c] = g;
    Gd[b * NC + c] = gd;
}

// ---------------- per-row broadcast vectors A (i), Bc (j), Dg (diag) ----------------
__global__ __launch_bounds__(256) void k_red3(
    const float* __restrict__ rsum, const float* __restrict__ pcsum,
    const float* __restrict__ diag, const float* __restrict__ Weq,
    float* __restrict__ A, float* __restrict__ Bc, float* __restrict__ Dgv)
{
    int row0 = blockIdx.x * 4;
    int tid = threadIdx.x;
    int c = tid & 127, half = tid >> 7;
    __shared__ float ds[4][NC], rs[4][NC], cs[4][NC];
    for (int idx = tid; idx < 4 * NC; idx += 256) {
        int r = idx >> 7, cc = idx & 127;
        size_t o = (size_t)(row0 + r) * NC + cc;
        ds[r][cc] = diag[o];
        rs[r][cc] = rsum[o];
        float s = 0.f;
        #pragma unroll
        for (int ch = 0; ch < 4; ++ch) s += pcsum[(size_t)ch * NB*NN*NC + o];
        cs[r][cc] = s / AVGF;
    }
    __syncthreads();
    float aA[2] = {0,0}, aB[2] = {0,0}, aD[2] = {0,0};
    for (int k = 0; k < NC; ++k) {
        float w2  = Weq[(2  * NC + k) * NC + c];
        float w3  = Weq[(3  * NC + k) * NC + c];
        float w4  = Weq[(4  * NC + k) * NC + c];
        float w5  = Weq[(5  * NC + k) * NC + c];
        float w6  = Weq[(6  * NC + k) * NC + c];
        float w7  = Weq[(7  * NC + k) * NC + c];
        float w8  = Weq[(8  * NC + k) * NC + c];
        float w9  = Weq[(9  * NC + k) * NC + c];
        float w10 = Weq[(10 * NC + k) * NC + c];
        #pragma unroll
        for (int r = 0; r < 2; ++r) {
            int rr = half * 2 + r;
            float dv = ds[rr][k], rv = rs[rr][k], cv = cs[rr][k];
            aA[r] += dv * w3 + rv * w5 + cv * w7;
            aB[r] += dv * w4 + rv * w6 + cv * w8;
            aD[r] += dv * w2 + rv * w9 + cv * w10;
        }
    }
    #pragma unroll
    for (int r = 0; r < 2; ++r) {
        size_t o = (size_t)(row0 + half * 2 + r) * NC + c;
        A[o] = aA[r];
        Bc[o] = aB[r];
        Dgv[o] = aD[r];
    }
}

// ---------------- Eq2to0 head + output MLP ----------------
__global__ __launch_bounds__(128) void k_final(
    const float* __restrict__ rsum, const float* __restrict__ diag,
    const float* __restrict__ w20, const float* __restrict__ b20,
    const float* __restrict__ wmlp, const float* __restrict__ bmlp,
    float* __restrict__ outp)
{
    int b = blockIdx.x;
    int c = threadIdx.x;
    __shared__ float agg0[NC], agg1[NC], act3[NC];
    float dgv = 0.f, tot = 0.f;
    for (int i = 0; i < NN; ++i) {
        dgv += diag[(size_t)(b * NN + i) * NC + c];
        tot += rsum[(size_t)(b * NN + i) * NC + c];
    }
    agg0[c] = lrelu(dgv / AVGF);
    agg1[c] = lrelu(tot / AVGF);
    __syncthreads();
    float a3 = b20[c];
    for (int k = 0; k < NC; ++k)
        a3 += agg0[k] * w20[k * NC + c] + agg1[k] * w20[(NC + k) * NC + c];
    act3[c] = a3;
    __syncthreads();
    if (c < 2) {
        float o = bmlp[c];
        for (int d = 0; d < NC; ++d) o += act3[d] * wmlp[d * 2 + c];
        outp[b * 2 + c] = o;
    }
}

extern "C" void kernel_launch(void* const* d_in, const int* in_sizes, int n_in,
                              void* d_out, int out_size, void* d_ws, size_t ws_size,
                              hipStream_t stream)
{
    const float* momenta = (const float*)d_in[0];
    const float* scalars = (const float*)d_in[1];
    const int*   nobj    = (const int*)d_in[2];
    const float* w_lin   = (const float*)d_in[3];
    const float* alpha   = (const float*)d_in[4];
    const float* w_in    = (const float*)d_in[5];
    const float* b_in    = (const float*)d_in[6];
    const float *msgW[4], *msgB[4], *eqW[4], *eqB[4], *eqBd[4];
    const float *wm0, *bm0, *w20, *b20, *wmlp, *bmlp;
    if (n_in >= 33) {
        for (int l = 0; l < 4; ++l) {
            msgW[l] = (const float*)d_in[7 + l];
            msgB[l] = (const float*)d_in[11 + l];
            eqW[l]  = (const float*)d_in[15 + l];
            eqB[l]  = (const float*)d_in[19 + l];
            eqBd[l] = (const float*)d_in[23 + l];
        }
        wm0  = (const float*)d_in[27]; bm0  = (const float*)d_in[28];
        w20  = (const float*)d_in[29]; b20  = (const float*)d_in[30];
        wmlp = (const float*)d_in[31]; bmlp = (const float*)d_in[32];
    } else {
        for (int l = 0; l < 4; ++l) {
            msgW[l] = (const float*)d_in[7] + (size_t)l * NC * NC;
            msgB[l] = (const float*)d_in[8] + l * NC;
            eqW[l]  = (const float*)d_in[9] + (size_t)l * 15 * NC * NC;
            eqB[l]  = (const float*)d_in[10] + l * NC;
            eqBd[l] = (const float*)d_in[11] + l * NC;
        }
        wm0  = (const float*)d_in[12]; bm0  = (const float*)d_in[13];
        w20  = (const float*)d_in[14]; b20  = (const float*)d_in[15];
        wmlp = (const float*)d_in[16]; bmlp = (const float*)d_in[17];
    }

    // ---- workspace layout ----
    const size_t TN2 = (size_t)NB * NN * TILE;       // shorts per tile array
    const size_t RN  = (size_t)NB * NN * NC;         // floats per row-vector array
    short* Xh = (short*)d_ws;
    short* Xl = Xh + TN2;
    short* Yh = Xl + TN2;
    short* Yl = Yh + TN2;
    short* SW = Yl + TN2;                            // 13 * 32768 shorts
    float* fp = (float*)(((uintptr_t)(SW + 13 * 32768) + 15) & ~(uintptr_t)15);
    float* rsum  = fp;
    float* pcsum = rsum + RN;                        // 4 chunks
    float* diag  = pcsum + 4 * RN;
    float* Aa    = diag + RN;
    float* Bb    = Aa + RN;
    float* Dgv   = Bb + RN;
    float* G     = Dgv + RN;
    float* Gd    = G + NB * NC;
    float* mask1 = Gd + NB * NC;
    float* P0    = mask1 + NB * NN;
    float* P1    = P0 + (size_t)NB * NN * NCS;
    float* P2    = P1 + (size_t)NB * NN * NCS;
    float* Ps3   = P2 + (size_t)NB * NN * NCS;
    float* Ps4   = Ps3 + NB * NCS;
    size_t need = (size_t)((char*)(Ps4 + NB * NCS) - (char*)d_ws);
    if (ws_size < need) return;

    k_split<<<dim3(64, 13), 256, 0, stream>>>(msgW[0], msgW[1], msgW[2], msgW[3],
                                              wm0, eqW[0], eqW[1], eqW[2], eqW[3], SW);
    k_prep<<<NB, 256, 0, stream>>>(scalars, nobj, w_in, mask1, P0, P1, P2, Ps3, Ps4);

    short* Wm0h = SW;                                 // msgW[0]
    k_f0<<<NB * NN, 512, 0, stream>>>(momenta, mask1, P0, P1, P2, Ps3, Ps4,
                                      b_in, w_lin, alpha, Wm0h, Wm0h + 16384,
                                      msgB[0], Xh, Xl, rsum, diag);

    short *inh = Xh, *inl = Xl, *outh = Yh, *outl = Yl;
    for (int l = 0; l < 4; ++l) {
        k_csum<<<512, 256, 0, stream>>>(inh, inl, pcsum);
        k_gg<<<NB, 128, 0, stream>>>(rsum, diag, eqW[l], eqB[l], eqBd[l], G, Gd);
        k_red3<<<NB * NN / 4, 256, 0, stream>>>(rsum, pcsum, diag, eqW[l], Aa, Bb, Dgv);
        short* W0 = SW + (size_t)(5 + 2 * l) * 32768;
        short* W1 = SW + (size_t)(6 + 2 * l) * 32768;
        if (l < 3) {
            short* Wm = SW + (size_t)(l + 1) * 32768;
            k_feq<1><<<NB * NN, 512, 0, stream>>>(inh, inl, W0, W0 + 16384,
                                                  W1, W1 + 16384, Wm, Wm + 16384,
                                                  msgB[l + 1], Aa, Bb, Dgv, G, Gd, mask1,
                                                  outh, outl, rsum, diag);
            short* th = inh; inh = outh; outh = th;
            short* tl = inl; inl = outl; outl = tl;
        } else {
            short* Wm = SW + (size_t)4 * 32768;       // wm0
            k_feq<0><<<NB * NN, 512, 0, stream>>>(inh, inl, W0, W0 + 16384,
                                                  W1, W1 + 16384, Wm, Wm + 16384,
                                                  bm0, Aa, Bb, Dgv, G, Gd, mask1,
                                                  outh, outl, rsum, diag);
        }
    }
    k_final<<<NB, 128, 0, stream>>>(rsum, diag, w20, b20, wmlp, bmlp, (float*)d_out);
}